// Round 5
// baseline (924.630 us; speedup 1.0000x reference)
//
#include <hip/hip_runtime.h>
#include <hip/hip_cooperative_groups.h>

namespace cg = cooperative_groups;

#define N_NODES 50000
#define N_EDGES 600000
#define E_PAD_MAX (N_EDGES + N_NODES * 7)   // padded edge capacity
#define CSR_BLOCKS 1792                      // 7 blocks/CU: co-resident for coop launch

using bf16x8 = __attribute__((ext_vector_type(8))) short;
using f32x4  = __attribute__((ext_vector_type(4))) float;
using f32x2  = __attribute__((ext_vector_type(2))) float;
typedef unsigned int uint32_tt;
typedef unsigned long long u64;

__device__ __forceinline__ unsigned short f2bf(float f) {
    union { float f; unsigned int u; } v; v.f = f;
    unsigned int u = v.u;
    return (unsigned short)((u + 0x7fffu + ((u >> 16) & 1u)) >> 16);  // RNE
}
__device__ __forceinline__ float bf2f(unsigned int h16) {
    union { unsigned int u; float f; } v; v.u = h16 << 16;
    return v.f;
}
// unpack 2 packed bf16 -> f32x2 {lo, hi}
__device__ __forceinline__ f32x2 unpk(uint32_tt w) {
    union { uint32_tt u; float f; } a, b;
    a.u = w << 16; b.u = w & 0xffff0000u;
    return (f32x2){a.f, b.f};
}

// ---------------- merged prep (runs FIRST, depends on nothing) ---------------
__global__ void prep_kernel(
    const float* __restrict__ x0, unsigned short* __restrict__ xb,
    const float* __restrict__ wr0, const float* __restrict__ wi0,
    const float* __restrict__ lw0, unsigned short* __restrict__ BT0,
    const float* __restrict__ wr1, const float* __restrict__ wi1,
    const float* __restrict__ lw1, unsigned short* __restrict__ BT1,
    const float* __restrict__ wr2, const float* __restrict__ wi2,
    const float* __restrict__ lw2, unsigned short* __restrict__ BT2,
    int* __restrict__ cnt, uint2* __restrict__ edat, int n) {
    int tid = blockIdx.x * 256 + threadIdx.x;
    int nth = gridDim.x * 256;
    for (int i = tid; i < N_NODES; i += nth) cnt[i] = 0;
    uint2 z; z.x = 0u; z.y = 0u;
    for (int i = tid; i < E_PAD_MAX; i += nth) edat[i] = z;

    int i = tid;
    int nconv = n * 96;
    if (i < nconv) {
        int r = i / 96, c = i - r * 96;
        xb[i] = (c < 75) ? f2bf(x0[r * 75 + c]) : (unsigned short)0;
        return;
    }
    i -= nconv;
    if (i < 128 * 288) {   // BT0: CIN=75 CINP=96 COUT=128
        int nn = i / 288, k = i - nn * 288;
        int part = k / 96, kk = k - part * 96;
        float v = 0.f;
        if (kk < 75) {
            if (part == 0)      v = wr0[kk * 128 + nn];
            else if (part == 1) v = -wi0[kk * 128 + nn];
            else                v = lw0[nn * 75 + kk];
        }
        BT0[i] = f2bf(v);
        return;
    }
    i -= 128 * 288;
    if (i < 128 * 384) {   // BT1: CIN=CINP=128 COUT=128
        int nn = i / 384, k = i - nn * 384;
        int part = k >> 7, kk = k & 127;
        float v;
        if (part == 0)      v = wr1[kk * 128 + nn];
        else if (part == 1) v = -wi1[kk * 128 + nn];
        else                v = lw1[nn * 128 + kk];
        BT1[i] = f2bf(v);
        return;
    }
    i -= 128 * 384;
    if (i < 96 * 128) {    // BT2 (Y-projection): [96 rows][128 k] = [wr2|-wi2|lw2^T]
        int nn = i >> 7, k = i & 127;
        float v;
        if (nn < 32)      v = wr2[k * 32 + nn];
        else if (nn < 64) v = -wi2[k * 32 + (nn - 32)];
        else              v = lw2[(nn - 64) * 128 + k];
        BT2[i] = f2bf(v);
    }
}

// ---------------- fused CSR build at FULL width (R17 fixed) ------------------
// R17 lesson refined: cooperative fusion failed at 256 blocks (1/CU, 11%
// occupancy -> 149us). The kernel is 8 VGPR / 1KB LDS, so 1792 blocks
// (7/CU, 28 waves/CU) are co-resident: hist/scatter phases run at ~full
// width, and we delete 3 launches + 3 drain gaps vs the 4-kernel chain.
// Scan: 1 element/thread (458752 threads >= n+1); block totals scanned by
// block 0 (1792 = 7*256 exactly).
__global__ __launch_bounds__(256) void graph_build(
    const int* __restrict__ ei, const float* __restrict__ w,
    const float* __restrict__ sim, int* __restrict__ cnt,
    int* __restrict__ rank, int* __restrict__ off,
    int* __restrict__ bscan, uint2* __restrict__ edat, int n, int E) {
    cg::grid_group grid = cg::this_grid();
    __shared__ int s[256];
    int t = threadIdx.x, b = blockIdx.x;
    int tid = b * 256 + t;
    int nth = gridDim.x * 256;

    // phase 1: histogram + per-edge rank (cnt zeroed by prep_kernel)
    for (int e = tid; e < E; e += nth)
        rank[e] = atomicAdd(&cnt[ei[E + e]], 1);
    grid.sync();

    // phase 2a: block-local inclusive scan of degrees padded to multiple of 8
    int i = tid;
    int deg = (i < n) ? ((cnt[i] + 7) & ~7) : 0;
    s[t] = deg;
    __syncthreads();
    for (int o = 1; o < 256; o <<= 1) {
        int tmp = (t >= o) ? s[t - o] : 0;
        __syncthreads();
        s[t] += tmp;
        __syncthreads();
    }
    int incl = s[t];
    if (t == 255) bscan[b] = incl;        // block total
    grid.sync();

    // phase 2b: block 0 turns the 1792 block totals into exclusive offsets
    if (b == 0) {
        int v[7]; int psum = 0;
#pragma unroll
        for (int k = 0; k < 7; ++k) { v[k] = bscan[t * 7 + k]; psum += v[k]; }
        s[t] = psum;
        __syncthreads();
        for (int o = 1; o < 256; o <<= 1) {
            int tmp = (t >= o) ? s[t - o] : 0;
            __syncthreads();
            s[t] += tmp;
            __syncthreads();
        }
        int run = s[t] - psum;            // exclusive over 7-chunks
#pragma unroll
        for (int k = 0; k < 7; ++k) { bscan[t * 7 + k] = run; run += v[k]; }
    }
    grid.sync();

    // phase 2c: write padded CSR offsets (i==n lands on total)
    if (i <= n) off[i] = bscan[b] + incl - deg;
    grid.sync();

    // phase 3: atomic-free scatter, p = off[d] + rank[e]
    for (int e = tid; e < E; e += nth) {
        int sid = ei[e], d = ei[E + e];
        int pos = off[d] + rank[e];
        float wt = w[e];
        uint2 m;
        m.x = (unsigned)sid;
        m.y = (uint32_tt)f2bf(wt * sim[2 * e]) |
              ((uint32_tt)f2bf(wt * sim[2 * e + 1]) << 16);
        edat[pos] = m;
    }
}

// ---------------- aggregation: one wave per node, edge-PAIR lanes ------------
// Verified plateau (R13/R15/R16/R18): 8 edges/iter, metadata in SGPRs via
// readfirstlane, 1-batch-ahead prefetch, L2-cached edat, 2 edges per gather
// inst, f32x2 packed accumulate. R18 A/B: packed FMA neutral vs scalar ->
// aggs are at the random-gather memory floor; do NOT spend more rounds on
// instruction shaving here. (R8 deep pipelining neutral; R14 2-waves
// regressed; R15 chunking+NT 2x regression.)
template <int CU2>  // uint32s per feature row (= CINP/2): 48 or 64
__global__ __launch_bounds__(256) void agg_pair(
    const uint32_tt* __restrict__ x, const int* __restrict__ off,
    const uint2* __restrict__ edat, uint32_tt* __restrict__ aggR,
    uint32_tt* __restrict__ aggI, int n) {
    constexpr int P = CU2 / 2;            // uint2 slots per row (24 or 32)
    constexpr int RB = CU2 * 4;           // row bytes (192 or 256)
    int wave = threadIdx.x >> 6;
    int lane = threadIdx.x & 63;
    int node = __builtin_amdgcn_readfirstlane(blockIdx.x * 4 + wave);
    if (node >= n) return;
    int j = lane >> 5;                    // edge slot within pair
    int c = lane & 31;
    int lc = (P == 32) ? c : (c < P ? c : P - 1);   // clamped uint2 slot
    f32x2 arA = (f32x2){0.f, 0.f}, arB = (f32x2){0.f, 0.f};
    f32x2 aiA = (f32x2){0.f, 0.f}, aiB = (f32x2){0.f, 0.f};
    int e0 = __builtin_amdgcn_readfirstlane(off[node]);
    int e1 = __builtin_amdgcn_readfirstlane(off[node + 1]);

    if (e0 < e1) {
        uint2 mn[8];
        int soc[4]; float crc[4], cic[4];
        uint2 wc[4];
        {
            uint2 m0[8];
#pragma unroll
            for (int k = 0; k < 8; ++k) m0[k] = edat[e0 + k];
            int so8[8]; float cr8[8], ci8[8];
#pragma unroll
            for (int k = 0; k < 8; ++k) {
                int s = __builtin_amdgcn_readfirstlane((int)m0[k].x);
                int pk = __builtin_amdgcn_readfirstlane((int)m0[k].y);
                so8[k] = s * RB;          // scalar multiply (SALU)
                cr8[k] = bf2f((unsigned)pk & 0xffffu);
                ci8[k] = bf2f((unsigned)pk >> 16);
            }
#pragma unroll
            for (int k = 0; k < 4; ++k) {   // per-half pair-member select
                soc[k] = j ? so8[2 * k + 1] : so8[2 * k];
                crc[k] = j ? cr8[2 * k + 1] : cr8[2 * k];
                cic[k] = j ? ci8[2 * k + 1] : ci8[2 * k];
            }
            int nb = (e0 + 8 < e1) ? e0 + 8 : e0;
#pragma unroll
            for (int k = 0; k < 8; ++k) mn[k] = edat[nb + k];
#pragma unroll
            for (int k = 0; k < 4; ++k)
                wc[k] = *(const uint2*)((const char*)x + (unsigned)soc[k] +
                                        (unsigned)(lc * 8));
        }
        for (int e = e0;; e += 8) {
            bool more = (e + 8 < e1);      // wave-uniform
            int son[4]; float crn[4], cin_[4]; uint2 wn[4];
            if (more) {
                int so8[8]; float cr8[8], ci8[8];
#pragma unroll
                for (int k = 0; k < 8; ++k) {
                    int s = __builtin_amdgcn_readfirstlane((int)mn[k].x);
                    int pk = __builtin_amdgcn_readfirstlane((int)mn[k].y);
                    so8[k] = s * RB;
                    cr8[k] = bf2f((unsigned)pk & 0xffffu);
                    ci8[k] = bf2f((unsigned)pk >> 16);
                }
#pragma unroll
                for (int k = 0; k < 4; ++k) {
                    son[k] = j ? so8[2 * k + 1] : so8[2 * k];
                    crn[k] = j ? cr8[2 * k + 1] : cr8[2 * k];
                    cin_[k] = j ? ci8[2 * k + 1] : ci8[2 * k];
                }
                int nb = (e + 16 < e1) ? e + 16 : e + 8;
#pragma unroll
                for (int k = 0; k < 8; ++k) mn[k] = edat[nb + k];
#pragma unroll
                for (int k = 0; k < 4; ++k)
                    wn[k] = *(const uint2*)((const char*)x + (unsigned)son[k] +
                                            (unsigned)(lc * 8));
            }
#pragma unroll
            for (int k = 0; k < 4; ++k) {
                f32x2 w0 = unpk(wc[k].x);          // {lo0, hi0}
                f32x2 w1 = unpk(wc[k].y);          // {lo1, hi1}
                f32x2 cr2 = (f32x2){crc[k], crc[k]};
                f32x2 ci2 = (f32x2){cic[k], cic[k]};
                arA = cr2 * w0 + arA;              // contracts to v_pk_fma_f32
                arB = cr2 * w1 + arB;
                aiA = ci2 * w0 + aiA;
                aiB = ci2 * w1 + aiB;
            }
            if (!more) break;
#pragma unroll
            for (int k = 0; k < 4; ++k) {
                crc[k] = crn[k]; cic[k] = cin_[k]; wc[k] = wn[k];
            }
        }
    }
    // combine the two edge-slot halves (lane l <-> l+32 share slot lc)
    float ar0 = arA.x, ar1 = arA.y, ar2 = arB.x, ar3 = arB.y;
    float ai0 = aiA.x, ai1 = aiA.y, ai2 = aiB.x, ai3 = aiB.y;
    ar0 += __shfl_xor(ar0, 32); ar1 += __shfl_xor(ar1, 32);
    ar2 += __shfl_xor(ar2, 32); ar3 += __shfl_xor(ar3, 32);
    ai0 += __shfl_xor(ai0, 32); ai1 += __shfl_xor(ai1, 32);
    ai2 += __shfl_xor(ai2, 32); ai3 += __shfl_xor(ai3, 32);
    if (lane < P) {
        uint2 oR, oI;
        oR.x = (uint32_tt)f2bf(ar0) | ((uint32_tt)f2bf(ar1) << 16);
        oR.y = (uint32_tt)f2bf(ar2) | ((uint32_tt)f2bf(ar3) << 16);
        oI.x = (uint32_tt)f2bf(ai0) | ((uint32_tt)f2bf(ai1) << 16);
        oI.y = (uint32_tt)f2bf(ai2) | ((uint32_tt)f2bf(ai3) << 16);
        ((uint2*)(aggR + (size_t)node * CU2))[lane] = oR;
        ((uint2*)(aggI + (size_t)node * CU2))[lane] = oI;
    }
}

// ---------------- layer-2 fused aggregate + bias + relu + store --------------
// Y [n][48 dwords]: 0-15 Yr, 16-31 Yin, 32-47 lin (bf16 pairs).
// Pair structure (R15): lanes 32-63 own the second edge of each pair.
// R16: packed f32x2 accumulate. Reduction: xor32 (edge slots) then xor16
// (cr*Yr + ci*Yi). DO NOT reintroduce lane-dependent selects across private
// arrays (R6/R12 demotion).
__global__ __launch_bounds__(256) void agg_out(
    const uint32_tt* __restrict__ Y, const int* __restrict__ off,
    const uint2* __restrict__ edat, const float* __restrict__ cb,
    const float* __restrict__ lb, float* __restrict__ out, int n) {
    int wave = threadIdx.x >> 6;
    int lane = threadIdx.x & 63;
    int node = __builtin_amdgcn_readfirstlane(blockIdx.x * 4 + wave);
    if (node >= n) return;
    int j = lane >> 5;                 // edge slot within pair
    int lc = lane & 31;                // dword within [Yr|Yi]
    int usei = lc >> 4;                // 0: Yr w/ cr, 1: Yi w/ ci
    f32x2 acc = (f32x2){0.f, 0.f};
    int e0 = __builtin_amdgcn_readfirstlane(off[node]);
    int e1 = __builtin_amdgcn_readfirstlane(off[node + 1]);

    if (e0 < e1) {
        uint2 mn[8];
        int soc[4]; float cc[4]; uint32_tt wc[4];
        {
            uint2 m0[8];
#pragma unroll
            for (int k = 0; k < 8; ++k) m0[k] = edat[e0 + k];
            int so8[8]; float cr8[8], ci8[8];
#pragma unroll
            for (int k = 0; k < 8; ++k) {
                int s = __builtin_amdgcn_readfirstlane((int)m0[k].x);
                int pk = __builtin_amdgcn_readfirstlane((int)m0[k].y);
                so8[k] = s * 192;      // Y row = 48 dwords
                cr8[k] = bf2f((unsigned)pk & 0xffffu);
                ci8[k] = bf2f((unsigned)pk >> 16);
            }
#pragma unroll
            for (int k = 0; k < 4; ++k) {
                soc[k] = j ? so8[2 * k + 1] : so8[2 * k];
                float a = j ? cr8[2 * k + 1] : cr8[2 * k];
                float b = j ? ci8[2 * k + 1] : ci8[2 * k];
                cc[k] = usei ? b : a;
            }
            int nb = (e0 + 8 < e1) ? e0 + 8 : e0;
#pragma unroll
            for (int k = 0; k < 8; ++k) mn[k] = edat[nb + k];
#pragma unroll
            for (int k = 0; k < 4; ++k)
                wc[k] = *(const uint32_tt*)((const char*)Y + (unsigned)soc[k] +
                                            (unsigned)(lc * 4));
        }
        for (int e = e0;; e += 8) {
            bool more = (e + 8 < e1);
            int son[4]; float cn[4]; uint32_tt wn[4];
            if (more) {
                int so8[8]; float cr8[8], ci8[8];
#pragma unroll
                for (int k = 0; k < 8; ++k) {
                    int s = __builtin_amdgcn_readfirstlane((int)mn[k].x);
                    int pk = __builtin_amdgcn_readfirstlane((int)mn[k].y);
                    so8[k] = s * 192;
                    cr8[k] = bf2f((unsigned)pk & 0xffffu);
                    ci8[k] = bf2f((unsigned)pk >> 16);
                }
#pragma unroll
                for (int k = 0; k < 4; ++k) {
                    son[k] = j ? so8[2 * k + 1] : so8[2 * k];
                    float a = j ? cr8[2 * k + 1] : cr8[2 * k];
                    float b = j ? ci8[2 * k + 1] : ci8[2 * k];
                    cn[k] = usei ? b : a;
                }
                int nb = (e + 16 < e1) ? e + 16 : e + 8;
#pragma unroll
                for (int k = 0; k < 8; ++k) mn[k] = edat[nb + k];
#pragma unroll
                for (int k = 0; k < 4; ++k)
                    wn[k] = *(const uint32_tt*)((const char*)Y + (unsigned)son[k] +
                                                (unsigned)(lc * 4));
            }
#pragma unroll
            for (int k = 0; k < 4; ++k) {
                f32x2 wv = unpk(wc[k]);
                f32x2 c2 = (f32x2){cc[k], cc[k]};
                acc = c2 * wv + acc;       // contracts to v_pk_fma_f32
            }
            if (!more) break;
#pragma unroll
            for (int k = 0; k < 4; ++k) { cc[k] = cn[k]; wc[k] = wn[k]; }
        }
    }
    // sum edge slots (xor 32), then combine cr*Yr + ci*Yi halves (xor 16)
    float alo = acc.x, ahi = acc.y;
    alo += __shfl_xor(alo, 32); alo += __shfl_xor(alo, 16);
    ahi += __shfl_xor(ahi, 32); ahi += __shfl_xor(ahi, 16);
    if (lane < 16) {
        uint32_tt lin = Y[(size_t)node * 48 + 32 + lane];
        int c0 = 2 * lane, c1 = 2 * lane + 1;
        float v0 = alo + bf2f(lin & 0xffffu) + cb[c0] + lb[c0];
        float v1 = ahi + bf2f(lin >> 16) + cb[c1] + lb[c1];
        float2 r;
        r.x = v0 > 0.f ? v0 : 0.f;
        r.y = v1 > 0.f ? v1 : 0.f;
        ((float2*)out)[(size_t)node * 16 + lane] = r;
    }
}

// ---------------- bf16 MFMA GEMM (layer 0) -----------------------------------
// R19: BM 128->64 (grid 391->782). At 391 blocks half the CUs got 2 blocks,
// half 1 -> ~25% tail on a latency-bound kernel. 782 blocks (~3/CU resident,
// LDS 15.4KB, acc 32 VGPR) overlap the chunk-staging latency.
template <int CINP, int COUT, int BM, int WM, int WN, int MT, int NT,
          bool OUT_BF16, bool RAW, int PARTS>
__global__ __launch_bounds__(256) void gemm_mfma(
    const unsigned short* __restrict__ A0, const unsigned short* __restrict__ A1,
    const unsigned short* __restrict__ A2, const unsigned short* __restrict__ BT,
    const float* __restrict__ cb, const float* __restrict__ lb,
    void* __restrict__ outv, int n) {
    constexpr int PK = 40;
    constexpr int KTOT = PARTS * CINP;
    constexpr int NCH = KTOT / 32;
    constexpr int CPP = CINP / 32;
    __shared__ unsigned short sA[BM][PK];
    __shared__ unsigned short sB[COUT][PK];

    int t = threadIdx.x;
    int lane = t & 63, wave = t >> 6;
    int wm = wave / WN, wn = wave % WN;
    int ml = lane & 15, kh = lane >> 4;
    int node0 = blockIdx.x * BM;

    const unsigned short* Asrc[3] = {A0, A1, A2};

    f32x4 acc[MT][NT];
#pragma unroll
    for (int mt = 0; mt < MT; ++mt)
#pragma unroll
        for (int nt = 0; nt < NT; ++nt) acc[mt][nt] = (f32x4){0.f, 0.f, 0.f, 0.f};

    for (int c = 0; c < NCH; ++c) {
        int part = (PARTS == 1) ? 0 : (c / CPP);
        int kk = (c - part * CPP) * 32;
        const unsigned short* __restrict__ Ap = Asrc[part];
        __syncthreads();
#pragma unroll
        for (int i = t; i < BM * 4; i += 256) {
            int r = i >> 2, q = i & 3;
            int node = node0 + r;
            if (node >= n) node = n - 1;
            *(uint4*)&sA[r][q * 8] =
                *(const uint4*)(Ap + (size_t)node * CINP + kk + q * 8);
        }
#pragma unroll
        for (int i = t; i < COUT * 4; i += 256) {
            int r = i >> 2, q = i & 3;
            *(uint4*)&sB[r][q * 8] =
                *(const uint4*)(BT + (size_t)r * KTOT + c * 32 + q * 8);
        }
        __syncthreads();
        bf16x8 af[MT], bfr[NT];
#pragma unroll
        for (int mt = 0; mt < MT; ++mt)
            af[mt] = *(const bf16x8*)&sA[wm * (MT * 16) + mt * 16 + ml][kh * 8];
#pragma unroll
        for (int nt = 0; nt < NT; ++nt)
            bfr[nt] = *(const bf16x8*)&sB[wn * (NT * 16) + nt * 16 + ml][kh * 8];
#pragma unroll
        for (int mt = 0; mt < MT; ++mt)
#pragma unroll
            for (int nt = 0; nt < NT; ++nt)
                acc[mt][nt] = __builtin_amdgcn_mfma_f32_16x16x32_bf16(
                    af[mt], bfr[nt], acc[mt][nt], 0, 0, 0);
    }

    int row0 = kh * 4;
#pragma unroll
    for (int nt = 0; nt < NT; ++nt) {
        int col = wn * (NT * 16) + nt * 16 + ml;
        float bias = RAW ? 0.f : (cb[col] + lb[col]);
#pragma unroll
        for (int mt = 0; mt < MT; ++mt) {
#pragma unroll
            for (int r = 0; r < 4; ++r) {
                int node = node0 + wm * (MT * 16) + mt * 16 + row0 + r;
                if (node < n) {
                    float v = acc[mt][nt][r] + bias;
                    if (!RAW) v = v > 0.f ? v : 0.f;
                    if (OUT_BF16)
                        ((unsigned short*)outv)[(size_t)node * COUT + col] = f2bf(v);
                    else
                        ((float*)outv)[(size_t)node * COUT + col] = v;
                }
            }
        }
    }
}

// ---------------- fused layer-1 GEMM + Y projection --------------------------
// Stage 1: h2 = relu([aggR|aggI|h1] @ BT1^T + b1)  -> LDS (bf16, never global)
// Stage 2: Y  = h2 @ BT2^T  (96 cols; BT2 frags from global, 24.6KB L1-hot)
__global__ __launch_bounds__(256) void gemm_l1y(
    const unsigned short* __restrict__ A0, const unsigned short* __restrict__ A1,
    const unsigned short* __restrict__ A2, const unsigned short* __restrict__ BT,
    const unsigned short* __restrict__ BT2, const float* __restrict__ cb,
    const float* __restrict__ lb, unsigned short* __restrict__ Yout, int n) {
    constexpr int PK = 40;
    constexpr int PH = 136;   // h2 LDS stride (16B-aligned rows)
    __shared__ unsigned short sA[128][PK];
    __shared__ unsigned short sB[128][PK];
    __shared__ unsigned short sH[128][PH];

    int t = threadIdx.x;
    int lane = t & 63, wave = t >> 6;
    int wm = wave >> 1, wn = wave & 1;
    int ml = lane & 15, kh = lane >> 4;
    int node0 = blockIdx.x * 128;
    const unsigned short* Asrc[3] = {A0, A1, A2};

    f32x4 acc[4][4];
#pragma unroll
    for (int mt = 0; mt < 4; ++mt)
#pragma unroll
        for (int nt = 0; nt < 4; ++nt) acc[mt][nt] = (f32x4){0.f, 0.f, 0.f, 0.f};

    for (int c = 0; c < 12; ++c) {          // KTOT=384, chunks of 32
        int part = c >> 2;
        int kk = (c & 3) * 32;
        const unsigned short* __restrict__ Ap = Asrc[part];
        __syncthreads();
#pragma unroll
        for (int i = t; i < 512; i += 256) {
            int r = i >> 2, q = i & 3;
            int node = node0 + r;
            if (node >= n) node = n - 1;
            *(uint4*)&sA[r][q * 8] =
                *(const uint4*)(Ap + (size_t)node * 128 + kk + q * 8);
        }
#pragma unroll
        for (int i = t; i < 512; i += 256) {
            int r = i >> 2, q = i & 3;
            *(uint4*)&sB[r][q * 8] =
                *(const uint4*)(BT + (size_t)r * 384 + c * 32 + q * 8);
        }
        __syncthreads();
        bf16x8 af[4], bfr[4];
#pragma unroll
        for (int mt = 0; mt < 4; ++mt)
            af[mt] = *(const bf16x8*)&sA[wm * 64 + mt * 16 + ml][kh * 8];
#pragma unroll
        for (int nt = 0; nt < 4; ++nt)
            bfr[nt] = *(const bf16x8*)&sB[wn * 64 + nt * 16 + ml][kh * 8];
#pragma unroll
        for (int mt = 0; mt < 4; ++mt)
#pragma unroll
            for (int nt = 0; nt < 4; ++nt)
                acc[mt][nt] = __builtin_amdgcn_mfma_f32_16x16x32_bf16(
                    af[mt], bfr[nt], acc[mt][nt], 0, 0, 0);
    }

    // epilogue 1: bias + relu -> bf16 -> sH[node][col]  (h2 stays on-chip)
    int row0 = kh * 4;
#pragma unroll
    for (int nt = 0; nt < 4; ++nt) {
        int col = wn * 64 + nt * 16 + ml;
        float bias = cb[col] + lb[col];
#pragma unroll
        for (int mt = 0; mt < 4; ++mt) {
#pragma unroll
            for (int r = 0; r < 4; ++r) {
                int nl = wm * 64 + mt * 16 + row0 + r;
                float v = acc[mt][nt][r] + bias;
                sH[nl][col] = f2bf(v > 0.f ? v : 0.f);
            }
        }
    }
    __syncthreads();

    // stage 2: Y[node][ycol] = sum_k h2[node][k] * BT2[ycol][k]
    f32x4 acc2[4][3];
#pragma unroll
    for (int mt = 0; mt < 4; ++mt)
#pragma unroll
        for (int nt = 0; nt < 3; ++nt) acc2[mt][nt] = (f32x4){0.f, 0.f, 0.f, 0.f};
    for (int c2 = 0; c2 < 4; ++c2) {
        bf16x8 af[4], bfr[3];
#pragma unroll
        for (int mt = 0; mt < 4; ++mt)
            af[mt] = *(const bf16x8*)&sH[wm * 64 + mt * 16 + ml][c2 * 32 + kh * 8];
#pragma unroll
        for (int nt = 0; nt < 3; ++nt) {
            int ycol = wn * 48 + nt * 16 + ml;
            bfr[nt] = *(const bf16x8*)(BT2 + (size_t)ycol * 128 + c2 * 32 + kh * 8);
        }
#pragma unroll
        for (int mt = 0; mt < 4; ++mt)
#pragma unroll
            for (int nt = 0; nt < 3; ++nt)
                acc2[mt][nt] = __builtin_amdgcn_mfma_f32_16x16x32_bf16(
                    af[mt], bfr[nt], acc2[mt][nt], 0, 0, 0);
    }
#pragma unroll
    for (int nt = 0; nt < 3; ++nt) {
        int ycol = wn * 48 + nt * 16 + ml;
#pragma unroll
        for (int mt = 0; mt < 4; ++mt) {
#pragma unroll
            for (int r = 0; r < 4; ++r) {
                int node = node0 + wm * 64 + mt * 16 + row0 + r;
                if (node < n)
                    Yout[(size_t)node * 96 + ycol] = f2bf(acc2[mt][nt][r]);
            }
        }
    }
}

// ---------------- launch ----------------

extern "C" void kernel_launch(void* const* d_in, const int* in_sizes, int n_in,
                              void* d_out, int out_size, void* d_ws, size_t ws_size,
                              hipStream_t stream) {
    const float* x0  = (const float*)d_in[0];
    const int*   ei  = (const int*)d_in[1];
    const float* wgt = (const float*)d_in[2];
    const float* sim = (const float*)d_in[3];
    const float *wr[3], *wi[3], *cb[3], *lw[3], *lb[3];
    for (int l = 0; l < 3; ++l) {
        wr[l] = (const float*)d_in[4 + 5 * l];
        wi[l] = (const float*)d_in[5 + 5 * l];
        cb[l] = (const float*)d_in[6 + 5 * l];
        lw[l] = (const float*)d_in[7 + 5 * l];
        lb[l] = (const float*)d_in[8 + 5 * l];
    }

    char* p = (char*)d_ws;
    auto alloc = [&](size_t bytes) -> void* {
        void* r = p;
        p += (bytes + 255) & ~(size_t)255;
        return r;
    };
    int*   off  = (int*)alloc((N_NODES + 1) * 4);
    int*   cnt  = (int*)alloc(N_NODES * 4);
    int*   bscan = (int*)alloc(CSR_BLOCKS * 4);
    int*   rank = (int*)alloc((size_t)N_EDGES * 4);
    uint2* edat = (uint2*)alloc((size_t)E_PAD_MAX * 8);
    unsigned short* xb    = (unsigned short*)alloc((size_t)N_NODES * 96 * 2);
    unsigned short* aggRb = (unsigned short*)alloc((size_t)N_NODES * 128 * 2);
    unsigned short* aggIb = (unsigned short*)alloc((size_t)N_NODES * 128 * 2);
    unsigned short* h1b   = (unsigned short*)alloc((size_t)N_NODES * 128 * 2);
    unsigned short* Yb    = (unsigned short*)alloc((size_t)N_NODES * 96 * 2);
    unsigned short* BT0   = (unsigned short*)alloc((size_t)128 * 288 * 2);
    unsigned short* BT1   = (unsigned short*)alloc((size_t)128 * 384 * 2);
    unsigned short* BT2   = (unsigned short*)alloc((size_t)96 * 128 * 2);
    float* outp = (float*)d_out;

    // merged prep FIRST (also zeroes cnt + edat; depends on nothing)
    {
        int total = N_NODES * 96 + 128 * 288 + 128 * 384 + 96 * 128;
        prep_kernel<<<(total + 255) / 256, 256, 0, stream>>>(
            x0, xb, wr[0], wi[0], lw[0], BT0, wr[1], wi[1], lw[1], BT1,
            wr[2], wi[2], lw[2], BT2, cnt, edat, N_NODES);
    }
    // fused CSR build at full co-resident width (1792 blocks = 7/CU)
    {
        int nN = N_NODES, nE = N_EDGES;
        void* args[] = {(void*)&ei, (void*)&wgt, (void*)&sim, (void*)&cnt,
                        (void*)&rank, (void*)&off, (void*)&bscan, (void*)&edat,
                        (void*)&nN, (void*)&nE};
        hipLaunchCooperativeKernel((const void*)graph_build, dim3(CSR_BLOCKS),
                                   dim3(256), args, 0, stream);
    }

    int agrid = (N_NODES + 3) / 4;

    // layer 0: xb [N,96] -> h1b [N,128]
    agg_pair<48><<<agrid, 256, 0, stream>>>((const uint32_tt*)xb, off, edat,
                                            (uint32_tt*)aggRb, (uint32_tt*)aggIb, N_NODES);
    gemm_mfma<96, 128, 64, 2, 2, 2, 4, true, false, 3>
        <<<(N_NODES + 63) / 64, 256, 0, stream>>>(aggRb, aggIb, xb, BT0, cb[0], lb[0],
                                                  h1b, N_NODES);
    // layer 1 + Y projection fused: h1b -> (h2 in LDS) -> Yb [N,96]
    agg_pair<64><<<agrid, 256, 0, stream>>>((const uint32_tt*)h1b, off, edat,
                                            (uint32_tt*)aggRb, (uint32_tt*)aggIb, N_NODES);
    gemm_l1y<<<(N_NODES + 127) / 128, 256, 0, stream>>>(aggRb, aggIb, h1b, BT1, BT2,
                                                        cb[1], lb[1], Yb, N_NODES);
    // layer 2: fused aggregate + bias + relu (edge pairs, no duplicate lanes)
    agg_out<<<agrid, 256, 0, stream>>>((const uint32_tt*)Yb, off, edat, cb[2], lb[2],
                                       outp, N_NODES);
}

// Round 8
// 259.879 us; speedup vs baseline: 3.5579x; 3.5579x over previous
//
#include <hip/hip_runtime.h>

#define N_NODES 50000
#define N_EDGES 600000
#define E_PAD_MAX (N_EDGES + N_NODES * 7)   // padded edge capacity

using bf16x8 = __attribute__((ext_vector_type(8))) short;
using f32x4  = __attribute__((ext_vector_type(4))) float;
using f32x2  = __attribute__((ext_vector_type(2))) float;
using u32x2  = __attribute__((ext_vector_type(2))) unsigned int;  // NT-store-able
typedef unsigned int uint32_tt;
typedef unsigned long long u64;

__device__ __forceinline__ unsigned short f2bf(float f) {
    union { float f; unsigned int u; } v; v.f = f;
    unsigned int u = v.u;
    return (unsigned short)((u + 0x7fffu + ((u >> 16) & 1u)) >> 16);  // RNE
}
__device__ __forceinline__ float bf2f(unsigned int h16) {
    union { unsigned int u; float f; } v; v.u = h16 << 16;
    return v.f;
}
// unpack 2 packed bf16 -> f32x2 {lo, hi}
__device__ __forceinline__ f32x2 unpk(uint32_tt w) {
    union { uint32_tt u; float f; } a, b;
    a.u = w << 16; b.u = w & 0xffff0000u;
    return (f32x2){a.f, b.f};
}

// ---------------- merged prep (runs FIRST, depends on nothing) ---------------
__global__ void prep_kernel(
    const float* __restrict__ x0, unsigned short* __restrict__ xb,
    const float* __restrict__ wr0, const float* __restrict__ wi0,
    const float* __restrict__ lw0, unsigned short* __restrict__ BT0,
    const float* __restrict__ wr1, const float* __restrict__ wi1,
    const float* __restrict__ lw1, unsigned short* __restrict__ BT1,
    const float* __restrict__ wr2, const float* __restrict__ wi2,
    const float* __restrict__ lw2, unsigned short* __restrict__ BT2,
    int* __restrict__ cnt, uint2* __restrict__ edat, int n) {
    int tid = blockIdx.x * 256 + threadIdx.x;
    int nth = gridDim.x * 256;
    for (int i = tid; i < N_NODES; i += nth) cnt[i] = 0;
    uint2 z; z.x = 0u; z.y = 0u;
    for (int i = tid; i < E_PAD_MAX; i += nth) edat[i] = z;

    int i = tid;
    int nconv = n * 96;
    if (i < nconv) {
        int r = i / 96, c = i - r * 96;
        xb[i] = (c < 75) ? f2bf(x0[r * 75 + c]) : (unsigned short)0;
        return;
    }
    i -= nconv;
    if (i < 128 * 288) {   // BT0: CIN=75 CINP=96 COUT=128
        int nn = i / 288, k = i - nn * 288;
        int part = k / 96, kk = k - part * 96;
        float v = 0.f;
        if (kk < 75) {
            if (part == 0)      v = wr0[kk * 128 + nn];
            else if (part == 1) v = -wi0[kk * 128 + nn];
            else                v = lw0[nn * 75 + kk];
        }
        BT0[i] = f2bf(v);
        return;
    }
    i -= 128 * 288;
    if (i < 128 * 384) {   // BT1: CIN=CINP=128 COUT=128
        int nn = i / 384, k = i - nn * 384;
        int part = k >> 7, kk = k & 127;
        float v;
        if (part == 0)      v = wr1[kk * 128 + nn];
        else if (part == 1) v = -wi1[kk * 128 + nn];
        else                v = lw1[nn * 128 + kk];
        BT1[i] = f2bf(v);
        return;
    }
    i -= 128 * 384;
    if (i < 96 * 128) {    // BT2 (Y-projection): [96 rows][128 k] = [wr2|-wi2|lw2^T]
        int nn = i >> 7, k = i & 127;
        float v;
        if (nn < 32)      v = wr2[k * 32 + nn];
        else if (nn < 64) v = -wi2[k * 32 + (nn - 32)];
        else              v = lw2[(nn - 64) * 128 + k];
        BT2[i] = f2bf(v);
    }
}

// ---------------- CSR build (degrees padded to multiple of 8) ----------------
// R17/R20 lessons: cooperative fusion is DEAD both ways. 256 blocks ->
// phases starve (149us, 11% occ). 1792 blocks -> grid.sync() itself costs
// ~680us (occ 85%, VALU 0.3%: resident-but-idle; device-wide barrier spin
// across 8 non-coherent XCD L2s). The 4-kernel chain at full grid width is
// the verified form. Do not revisit.

__global__ void hist_kernel(const int* __restrict__ ei, int* __restrict__ cnt,
                            int* __restrict__ rank, int E) {
    int e = blockIdx.x * 256 + threadIdx.x;
    if (e < E) rank[e] = atomicAdd(&cnt[ei[E + e]], 1);
}

__global__ void scan1(const int* __restrict__ deg, int* __restrict__ out,
                      int* __restrict__ bsum, int n) {
    __shared__ int s[256];
    int t = threadIdx.x;
    int base = blockIdx.x * 1024 + t * 4;
    int v0 = (base + 0 < n) ? ((deg[base + 0] + 7) & ~7) : 0;
    int v1 = (base + 1 < n) ? ((deg[base + 1] + 7) & ~7) : 0;
    int v2 = (base + 2 < n) ? ((deg[base + 2] + 7) & ~7) : 0;
    int v3 = (base + 3 < n) ? ((deg[base + 3] + 7) & ~7) : 0;
    int tsum = v0 + v1 + v2 + v3;
    s[t] = tsum;
    __syncthreads();
    for (int off = 1; off < 256; off <<= 1) {
        int tmp = (t >= off) ? s[t - off] : 0;
        __syncthreads();
        s[t] += tmp;
        __syncthreads();
    }
    int excl = s[t] - tsum;
    if (base + 0 < n) out[base + 0] = excl;
    if (base + 1 < n) out[base + 1] = excl + v0;
    if (base + 2 < n) out[base + 2] = excl + v0 + v1;
    if (base + 3 < n) out[base + 3] = excl + v0 + v1 + v2;
    if (t == 255) bsum[blockIdx.x] = s[255];
}

// scan3 with scan2 folded in (thread 0 sums <=49 L2-hot block totals)
__global__ void scan3(int* __restrict__ off, const int* __restrict__ bsum,
                      int n, int nb) {
    __shared__ int sp;
    int b = blockIdx.x, t = threadIdx.x;
    int seg = b >> 2;
    if (t == 0) {
        int acc = 0;
        for (int k = 0; k < seg; ++k) acc += bsum[k];
        sp = acc;
    }
    __syncthreads();
    int i = b * 256 + t;
    if (i < n) off[i] += sp;
    if (i == n) {
        int tot = sp;
        for (int k = seg; k < nb; ++k) tot += bsum[k];
        off[n] = tot;
    }
}

// atomic-free scatter: p = off[d] + rank[e]
__global__ void scatter_kernel(const int* __restrict__ ei, const float* __restrict__ w,
                               const float* __restrict__ sim, const int* __restrict__ off,
                               const int* __restrict__ rank, uint2* __restrict__ edat,
                               int E) {
    int e = blockIdx.x * 256 + threadIdx.x;
    if (e >= E) return;
    int s = ei[e], d = ei[E + e];
    int p = off[d] + rank[e];
    float wt = w[e];
    uint2 m;
    m.x = (unsigned)s;
    m.y = (uint32_tt)f2bf(wt * sim[2 * e]) |
          ((uint32_tt)f2bf(wt * sim[2 * e + 1]) << 16);
    edat[p] = m;
}

// ---------------- aggregation: one wave per node, edge-PAIR lanes ------------
// Verified plateau (R13/R15/R16/R18): 8 edges/iter, metadata in SGPRs via
// readfirstlane, 1-batch-ahead prefetch, L2-cached edat, 2 edges per gather
// inst, f32x2 packed accumulate (neutral but kept: fewer ops, same time).
// R21: NT stores on agg outputs (via clang ext_vector u32x2 — HIP's uint2
// class type is rejected by the builtin, R22 compile fix). The output stream
// (19-26MB/pass) is 1.5-2x the gather table (9.6-12.8MB) and consumed
// exactly once by the next GEMM; regular stores evict the gather-hot table
// from the 4MB/XCD L2. NT stores keep the table resident. (Distinct from
// R15's NT-LOAD regression: that put HBM latency on the serial edat chain.)
template <int CU2>  // uint32s per feature row (= CINP/2): 48 or 64
__global__ __launch_bounds__(256) void agg_pair(
    const uint32_tt* __restrict__ x, const int* __restrict__ off,
    const uint2* __restrict__ edat, uint32_tt* __restrict__ aggR,
    uint32_tt* __restrict__ aggI, int n) {
    constexpr int P = CU2 / 2;            // uint2 slots per row (24 or 32)
    constexpr int RB = CU2 * 4;           // row bytes (192 or 256)
    int wave = threadIdx.x >> 6;
    int lane = threadIdx.x & 63;
    int node = __builtin_amdgcn_readfirstlane(blockIdx.x * 4 + wave);
    if (node >= n) return;
    int j = lane >> 5;                    // edge slot within pair
    int c = lane & 31;
    int lc = (P == 32) ? c : (c < P ? c : P - 1);   // clamped uint2 slot
    f32x2 arA = (f32x2){0.f, 0.f}, arB = (f32x2){0.f, 0.f};
    f32x2 aiA = (f32x2){0.f, 0.f}, aiB = (f32x2){0.f, 0.f};
    int e0 = __builtin_amdgcn_readfirstlane(off[node]);
    int e1 = __builtin_amdgcn_readfirstlane(off[node + 1]);

    if (e0 < e1) {
        uint2 mn[8];
        int soc[4]; float crc[4], cic[4];
        uint2 wc[4];
        {
            uint2 m0[8];
#pragma unroll
            for (int k = 0; k < 8; ++k) m0[k] = edat[e0 + k];
            int so8[8]; float cr8[8], ci8[8];
#pragma unroll
            for (int k = 0; k < 8; ++k) {
                int s = __builtin_amdgcn_readfirstlane((int)m0[k].x);
                int pk = __builtin_amdgcn_readfirstlane((int)m0[k].y);
                so8[k] = s * RB;          // scalar multiply (SALU)
                cr8[k] = bf2f((unsigned)pk & 0xffffu);
                ci8[k] = bf2f((unsigned)pk >> 16);
            }
#pragma unroll
            for (int k = 0; k < 4; ++k) {   // per-half pair-member select
                soc[k] = j ? so8[2 * k + 1] : so8[2 * k];
                crc[k] = j ? cr8[2 * k + 1] : cr8[2 * k];
                cic[k] = j ? ci8[2 * k + 1] : ci8[2 * k];
            }
            int nb = (e0 + 8 < e1) ? e0 + 8 : e0;
#pragma unroll
            for (int k = 0; k < 8; ++k) mn[k] = edat[nb + k];
#pragma unroll
            for (int k = 0; k < 4; ++k)
                wc[k] = *(const uint2*)((const char*)x + (unsigned)soc[k] +
                                        (unsigned)(lc * 8));
        }
        for (int e = e0;; e += 8) {
            bool more = (e + 8 < e1);      // wave-uniform
            int son[4]; float crn[4], cin_[4]; uint2 wn[4];
            if (more) {
                int so8[8]; float cr8[8], ci8[8];
#pragma unroll
                for (int k = 0; k < 8; ++k) {
                    int s = __builtin_amdgcn_readfirstlane((int)mn[k].x);
                    int pk = __builtin_amdgcn_readfirstlane((int)mn[k].y);
                    so8[k] = s * RB;
                    cr8[k] = bf2f((unsigned)pk & 0xffffu);
                    ci8[k] = bf2f((unsigned)pk >> 16);
                }
#pragma unroll
                for (int k = 0; k < 4; ++k) {
                    son[k] = j ? so8[2 * k + 1] : so8[2 * k];
                    crn[k] = j ? cr8[2 * k + 1] : cr8[2 * k];
                    cin_[k] = j ? ci8[2 * k + 1] : ci8[2 * k];
                }
                int nb = (e + 16 < e1) ? e + 16 : e + 8;
#pragma unroll
                for (int k = 0; k < 8; ++k) mn[k] = edat[nb + k];
#pragma unroll
                for (int k = 0; k < 4; ++k)
                    wn[k] = *(const uint2*)((const char*)x + (unsigned)son[k] +
                                            (unsigned)(lc * 8));
            }
#pragma unroll
            for (int k = 0; k < 4; ++k) {
                f32x2 w0 = unpk(wc[k].x);          // {lo0, hi0}
                f32x2 w1 = unpk(wc[k].y);          // {lo1, hi1}
                f32x2 cr2 = (f32x2){crc[k], crc[k]};
                f32x2 ci2 = (f32x2){cic[k], cic[k]};
                arA = cr2 * w0 + arA;              // contracts to v_pk_fma_f32
                arB = cr2 * w1 + arB;
                aiA = ci2 * w0 + aiA;
                aiB = ci2 * w1 + aiB;
            }
            if (!more) break;
#pragma unroll
            for (int k = 0; k < 4; ++k) {
                crc[k] = crn[k]; cic[k] = cin_[k]; wc[k] = wn[k];
            }
        }
    }
    // combine the two edge-slot halves (lane l <-> l+32 share slot lc)
    float ar0 = arA.x, ar1 = arA.y, ar2 = arB.x, ar3 = arB.y;
    float ai0 = aiA.x, ai1 = aiA.y, ai2 = aiB.x, ai3 = aiB.y;
    ar0 += __shfl_xor(ar0, 32); ar1 += __shfl_xor(ar1, 32);
    ar2 += __shfl_xor(ar2, 32); ar3 += __shfl_xor(ar3, 32);
    ai0 += __shfl_xor(ai0, 32); ai1 += __shfl_xor(ai1, 32);
    ai2 += __shfl_xor(ai2, 32); ai3 += __shfl_xor(ai3, 32);
    if (lane < P) {
        u32x2 oR, oI;
        oR.x = (uint32_tt)f2bf(ar0) | ((uint32_tt)f2bf(ar1) << 16);
        oR.y = (uint32_tt)f2bf(ar2) | ((uint32_tt)f2bf(ar3) << 16);
        oI.x = (uint32_tt)f2bf(ai0) | ((uint32_tt)f2bf(ai1) << 16);
        oI.y = (uint32_tt)f2bf(ai2) | ((uint32_tt)f2bf(ai3) << 16);
        __builtin_nontemporal_store(oR, (u32x2*)(aggR + (size_t)node * CU2) + lane);
        __builtin_nontemporal_store(oI, (u32x2*)(aggI + (size_t)node * CU2) + lane);
    }
}

// ---------------- layer-2 fused aggregate + bias + relu + store --------------
// Y [n][48 dwords]: 0-15 Yr, 16-31 Yin, 32-47 lin (bf16 pairs).
// Pair structure (R15): lanes 32-63 own the second edge of each pair.
// R16: packed f32x2 accumulate. Reduction: xor32 (edge slots) then xor16
// (cr*Yr + ci*Yi). DO NOT reintroduce lane-dependent selects across private
// arrays (R6/R12 demotion).
__global__ __launch_bounds__(256) void agg_out(
    const uint32_tt* __restrict__ Y, const int* __restrict__ off,
    const uint2* __restrict__ edat, const float* __restrict__ cb,
    const float* __restrict__ lb, float* __restrict__ out, int n) {
    int wave = threadIdx.x >> 6;
    int lane = threadIdx.x & 63;
    int node = __builtin_amdgcn_readfirstlane(blockIdx.x * 4 + wave);
    if (node >= n) return;
    int j = lane >> 5;                 // edge slot within pair
    int lc = lane & 31;                // dword within [Yr|Yi]
    int usei = lc >> 4;                // 0: Yr w/ cr, 1: Yi w/ ci
    f32x2 acc = (f32x2){0.f, 0.f};
    int e0 = __builtin_amdgcn_readfirstlane(off[node]);
    int e1 = __builtin_amdgcn_readfirstlane(off[node + 1]);

    if (e0 < e1) {
        uint2 mn[8];
        int soc[4]; float cc[4]; uint32_tt wc[4];
        {
            uint2 m0[8];
#pragma unroll
            for (int k = 0; k < 8; ++k) m0[k] = edat[e0 + k];
            int so8[8]; float cr8[8], ci8[8];
#pragma unroll
            for (int k = 0; k < 8; ++k) {
                int s = __builtin_amdgcn_readfirstlane((int)m0[k].x);
                int pk = __builtin_amdgcn_readfirstlane((int)m0[k].y);
                so8[k] = s * 192;      // Y row = 48 dwords
                cr8[k] = bf2f((unsigned)pk & 0xffffu);
                ci8[k] = bf2f((unsigned)pk >> 16);
            }
#pragma unroll
            for (int k = 0; k < 4; ++k) {
                soc[k] = j ? so8[2 * k + 1] : so8[2 * k];
                float a = j ? cr8[2 * k + 1] : cr8[2 * k];
                float b = j ? ci8[2 * k + 1] : ci8[2 * k];
                cc[k] = usei ? b : a;
            }
            int nb = (e0 + 8 < e1) ? e0 + 8 : e0;
#pragma unroll
            for (int k = 0; k < 8; ++k) mn[k] = edat[nb + k];
#pragma unroll
            for (int k = 0; k < 4; ++k)
                wc[k] = *(const uint32_tt*)((const char*)Y + (unsigned)soc[k] +
                                            (unsigned)(lc * 4));
        }
        for (int e = e0;; e += 8) {
            bool more = (e + 8 < e1);
            int son[4]; float cn[4]; uint32_tt wn[4];
            if (more) {
                int so8[8]; float cr8[8], ci8[8];
#pragma unroll
                for (int k = 0; k < 8; ++k) {
                    int s = __builtin_amdgcn_readfirstlane((int)mn[k].x);
                    int pk = __builtin_amdgcn_readfirstlane((int)mn[k].y);
                    so8[k] = s * 192;
                    cr8[k] = bf2f((unsigned)pk & 0xffffu);
                    ci8[k] = bf2f((unsigned)pk >> 16);
                }
#pragma unroll
                for (int k = 0; k < 4; ++k) {
                    son[k] = j ? so8[2 * k + 1] : so8[2 * k];
                    float a = j ? cr8[2 * k + 1] : cr8[2 * k];
                    float b = j ? ci8[2 * k + 1] : ci8[2 * k];
                    cn[k] = usei ? b : a;
                }
                int nb = (e + 16 < e1) ? e + 16 : e + 8;
#pragma unroll
                for (int k = 0; k < 8; ++k) mn[k] = edat[nb + k];
#pragma unroll
                for (int k = 0; k < 4; ++k)
                    wn[k] = *(const uint32_tt*)((const char*)Y + (unsigned)son[k] +
                                                (unsigned)(lc * 4));
            }
#pragma unroll
            for (int k = 0; k < 4; ++k) {
                f32x2 wv = unpk(wc[k]);
                f32x2 c2 = (f32x2){cc[k], cc[k]};
                acc = c2 * wv + acc;       // contracts to v_pk_fma_f32
            }
            if (!more) break;
#pragma unroll
            for (int k = 0; k < 4; ++k) { cc[k] = cn[k]; wc[k] = wn[k]; }
        }
    }
    // sum edge slots (xor 32), then combine cr*Yr + ci*Yi halves (xor 16)
    float alo = acc.x, ahi = acc.y;
    alo += __shfl_xor(alo, 32); alo += __shfl_xor(alo, 16);
    ahi += __shfl_xor(ahi, 32); ahi += __shfl_xor(ahi, 16);
    if (lane < 16) {
        uint32_tt lin = Y[(size_t)node * 48 + 32 + lane];
        int c0 = 2 * lane, c1 = 2 * lane + 1;
        float v0 = alo + bf2f(lin & 0xffffu) + cb[c0] + lb[c0];
        float v1 = ahi + bf2f(lin >> 16) + cb[c1] + lb[c1];
        float2 r;
        r.x = v0 > 0.f ? v0 : 0.f;
        r.y = v1 > 0.f ? v1 : 0.f;
        ((float2*)out)[(size_t)node * 16 + lane] = r;
    }
}

// ---------------- bf16 MFMA GEMM (layer 0) -----------------------------------
// R20: BM=64 A/B was neutral-to-slightly-worse; BM=128 is the verified form.
template <int CINP, int COUT, int BM, int WM, int WN, int MT, int NT,
          bool OUT_BF16, bool RAW, int PARTS>
__global__ __launch_bounds__(256) void gemm_mfma(
    const unsigned short* __restrict__ A0, const unsigned short* __restrict__ A1,
    const unsigned short* __restrict__ A2, const unsigned short* __restrict__ BT,
    const float* __restrict__ cb, const float* __restrict__ lb,
    void* __restrict__ outv, int n) {
    constexpr int PK = 40;
    constexpr int KTOT = PARTS * CINP;
    constexpr int NCH = KTOT / 32;
    constexpr int CPP = CINP / 32;
    __shared__ unsigned short sA[BM][PK];
    __shared__ unsigned short sB[COUT][PK];

    int t = threadIdx.x;
    int lane = t & 63, wave = t >> 6;
    int wm = wave / WN, wn = wave % WN;
    int ml = lane & 15, kh = lane >> 4;
    int node0 = blockIdx.x * BM;

    const unsigned short* Asrc[3] = {A0, A1, A2};

    f32x4 acc[MT][NT];
#pragma unroll
    for (int mt = 0; mt < MT; ++mt)
#pragma unroll
        for (int nt = 0; nt < NT; ++nt) acc[mt][nt] = (f32x4){0.f, 0.f, 0.f, 0.f};

    for (int c = 0; c < NCH; ++c) {
        int part = (PARTS == 1) ? 0 : (c / CPP);
        int kk = (c - part * CPP) * 32;
        const unsigned short* __restrict__ Ap = Asrc[part];
        __syncthreads();
#pragma unroll
        for (int i = t; i < BM * 4; i += 256) {
            int r = i >> 2, q = i & 3;
            int node = node0 + r;
            if (node >= n) node = n - 1;
            *(uint4*)&sA[r][q * 8] =
                *(const uint4*)(Ap + (size_t)node * CINP + kk + q * 8);
        }
#pragma unroll
        for (int i = t; i < COUT * 4; i += 256) {
            int r = i >> 2, q = i & 3;
            *(uint4*)&sB[r][q * 8] =
                *(const uint4*)(BT + (size_t)r * KTOT + c * 32 + q * 8);
        }
        __syncthreads();
        bf16x8 af[MT], bfr[NT];
#pragma unroll
        for (int mt = 0; mt < MT; ++mt)
            af[mt] = *(const bf16x8*)&sA[wm * (MT * 16) + mt * 16 + ml][kh * 8];
#pragma unroll
        for (int nt = 0; nt < NT; ++nt)
            bfr[nt] = *(const bf16x8*)&sB[wn * (NT * 16) + nt * 16 + ml][kh * 8];
#pragma unroll
        for (int mt = 0; mt < MT; ++mt)
#pragma unroll
            for (int nt = 0; nt < NT; ++nt)
                acc[mt][nt] = __builtin_amdgcn_mfma_f32_16x16x32_bf16(
                    af[mt], bfr[nt], acc[mt][nt], 0, 0, 0);
    }

    int row0 = kh * 4;
#pragma unroll
    for (int nt = 0; nt < NT; ++nt) {
        int col = wn * (NT * 16) + nt * 16 + ml;
        float bias = RAW ? 0.f : (cb[col] + lb[col]);
#pragma unroll
        for (int mt = 0; mt < MT; ++mt) {
#pragma unroll
            for (int r = 0; r < 4; ++r) {
                int node = node0 + wm * (MT * 16) + mt * 16 + row0 + r;
                if (node < n) {
                    float v = acc[mt][nt][r] + bias;
                    if (!RAW) v = v > 0.f ? v : 0.f;
                    if (OUT_BF16)
                        ((unsigned short*)outv)[(size_t)node * COUT + col] = f2bf(v);
                    else
                        ((float*)outv)[(size_t)node * COUT + col] = v;
                }
            }
        }
    }
}

// ---------------- fused layer-1 GEMM + Y projection --------------------------
// Stage 1: h2 = relu([aggR|aggI|h1] @ BT1^T + b1)  -> LDS (bf16, never global)
// Stage 2: Y  = h2 @ BT2^T  (96 cols; BT2 frags from global, 24.6KB L1-hot)
__global__ __launch_bounds__(256) void gemm_l1y(
    const unsigned short* __restrict__ A0, const unsigned short* __restrict__ A1,
    const unsigned short* __restrict__ A2, const unsigned short* __restrict__ BT,
    const unsigned short* __restrict__ BT2, const float* __restrict__ cb,
    const float* __restrict__ lb, unsigned short* __restrict__ Yout, int n) {
    constexpr int PK = 40;
    constexpr int PH = 136;   // h2 LDS stride (16B-aligned rows)
    __shared__ unsigned short sA[128][PK];
    __shared__ unsigned short sB[128][PK];
    __shared__ unsigned short sH[128][PH];

    int t = threadIdx.x;
    int lane = t & 63, wave = t >> 6;
    int wm = wave >> 1, wn = wave & 1;
    int ml = lane & 15, kh = lane >> 4;
    int node0 = blockIdx.x * 128;
    const unsigned short* Asrc[3] = {A0, A1, A2};

    f32x4 acc[4][4];
#pragma unroll
    for (int mt = 0; mt < 4; ++mt)
#pragma unroll
        for (int nt = 0; nt < 4; ++nt) acc[mt][nt] = (f32x4){0.f, 0.f, 0.f, 0.f};

    for (int c = 0; c < 12; ++c) {          // KTOT=384, chunks of 32
        int part = c >> 2;
        int kk = (c & 3) * 32;
        const unsigned short* __restrict__ Ap = Asrc[part];
        __syncthreads();
#pragma unroll
        for (int i = t; i < 512; i += 256) {
            int r = i >> 2, q = i & 3;
            int node = node0 + r;
            if (node >= n) node = n - 1;
            *(uint4*)&sA[r][q * 8] =
                *(const uint4*)(Ap + (size_t)node * 128 + kk + q * 8);
        }
#pragma unroll
        for (int i = t; i < 512; i += 256) {
            int r = i >> 2, q = i & 3;
            *(uint4*)&sB[r][q * 8] =
                *(const uint4*)(BT + (size_t)r * 384 + c * 32 + q * 8);
        }
        __syncthreads();
        bf16x8 af[4], bfr[4];
#pragma unroll
        for (int mt = 0; mt < 4; ++mt)
            af[mt] = *(const bf16x8*)&sA[wm * 64 + mt * 16 + ml][kh * 8];
#pragma unroll
        for (int nt = 0; nt < 4; ++nt)
            bfr[nt] = *(const bf16x8*)&sB[wn * 64 + nt * 16 + ml][kh * 8];
#pragma unroll
        for (int mt = 0; mt < 4; ++mt)
#pragma unroll
            for (int nt = 0; nt < 4; ++nt)
                acc[mt][nt] = __builtin_amdgcn_mfma_f32_16x16x32_bf16(
                    af[mt], bfr[nt], acc[mt][nt], 0, 0, 0);
    }

    // epilogue 1: bias + relu -> bf16 -> sH[node][col]  (h2 stays on-chip)
    int row0 = kh * 4;
#pragma unroll
    for (int nt = 0; nt < 4; ++nt) {
        int col = wn * 64 + nt * 16 + ml;
        float bias = cb[col] + lb[col];
#pragma unroll
        for (int mt = 0; mt < 4; ++mt) {
#pragma unroll
            for (int r = 0; r < 4; ++r) {
                int nl = wm * 64 + mt * 16 + row0 + r;
                float v = acc[mt][nt][r] + bias;
                sH[nl][col] = f2bf(v > 0.f ? v : 0.f);
            }
        }
    }
    __syncthreads();

    // stage 2: Y[node][ycol] = sum_k h2[node][k] * BT2[ycol][k]
    f32x4 acc2[4][3];
#pragma unroll
    for (int mt = 0; mt < 4; ++mt)
#pragma unroll
        for (int nt = 0; nt < 3; ++nt) acc2[mt][nt] = (f32x4){0.f, 0.f, 0.f, 0.f};
    for (int c2 = 0; c2 < 4; ++c2) {
        bf16x8 af[4], bfr[3];
#pragma unroll
        for (int mt = 0; mt < 4; ++mt)
            af[mt] = *(const bf16x8*)&sH[wm * 64 + mt * 16 + ml][c2 * 32 + kh * 8];
#pragma unroll
        for (int nt = 0; nt < 3; ++nt) {
            int ycol = wn * 48 + nt * 16 + ml;
            bfr[nt] = *(const bf16x8*)(BT2 + (size_t)ycol * 128 + c2 * 32 + kh * 8);
        }
#pragma unroll
        for (int mt = 0; mt < 4; ++mt)
#pragma unroll
            for (int nt = 0; nt < 3; ++nt)
                acc2[mt][nt] = __builtin_amdgcn_mfma_f32_16x16x32_bf16(
                    af[mt], bfr[nt], acc2[mt][nt], 0, 0, 0);
    }
#pragma unroll
    for (int nt = 0; nt < 3; ++nt) {
        int ycol = wn * 48 + nt * 16 + ml;
#pragma unroll
        for (int mt = 0; mt < 4; ++mt) {
#pragma unroll
            for (int r = 0; r < 4; ++r) {
                int node = node0 + wm * 64 + mt * 16 + row0 + r;
                if (node < n)
                    Yout[(size_t)node * 96 + ycol] = f2bf(acc2[mt][nt][r]);
            }
        }
    }
}

// ---------------- launch ----------------

extern "C" void kernel_launch(void* const* d_in, const int* in_sizes, int n_in,
                              void* d_out, int out_size, void* d_ws, size_t ws_size,
                              hipStream_t stream) {
    const float* x0  = (const float*)d_in[0];
    const int*   ei  = (const int*)d_in[1];
    const float* wgt = (const float*)d_in[2];
    const float* sim = (const float*)d_in[3];
    const float *wr[3], *wi[3], *cb[3], *lw[3], *lb[3];
    for (int l = 0; l < 3; ++l) {
        wr[l] = (const float*)d_in[4 + 5 * l];
        wi[l] = (const float*)d_in[5 + 5 * l];
        cb[l] = (const float*)d_in[6 + 5 * l];
        lw[l] = (const float*)d_in[7 + 5 * l];
        lb[l] = (const float*)d_in[8 + 5 * l];
    }

    char* p = (char*)d_ws;
    auto alloc = [&](size_t bytes) -> void* {
        void* r = p;
        p += (bytes + 255) & ~(size_t)255;
        return r;
    };
    int*   off  = (int*)alloc((N_NODES + 1) * 4);
    int*   cnt  = (int*)alloc(N_NODES * 4);
    int*   bsum = (int*)alloc(256);
    int*   rank = (int*)alloc((size_t)N_EDGES * 4);
    uint2* edat = (uint2*)alloc((size_t)E_PAD_MAX * 8);
    unsigned short* xb    = (unsigned short*)alloc((size_t)N_NODES * 96 * 2);
    unsigned short* aggRb = (unsigned short*)alloc((size_t)N_NODES * 128 * 2);
    unsigned short* aggIb = (unsigned short*)alloc((size_t)N_NODES * 128 * 2);
    unsigned short* h1b   = (unsigned short*)alloc((size_t)N_NODES * 128 * 2);
    unsigned short* Yb    = (unsigned short*)alloc((size_t)N_NODES * 96 * 2);
    unsigned short* BT0   = (unsigned short*)alloc((size_t)128 * 288 * 2);
    unsigned short* BT1   = (unsigned short*)alloc((size_t)128 * 384 * 2);
    unsigned short* BT2   = (unsigned short*)alloc((size_t)96 * 128 * 2);
    float* outp = (float*)d_out;

    // merged prep FIRST (also zeroes cnt + edat; depends on nothing)
    {
        int total = N_NODES * 96 + 128 * 288 + 128 * 384 + 96 * 128;
        prep_kernel<<<(total + 255) / 256, 256, 0, stream>>>(
            x0, xb, wr[0], wi[0], lw[0], BT0, wr[1], wi[1], lw[1], BT1,
            wr[2], wi[2], lw[2], BT2, cnt, edat, N_NODES);
    }
    // CSR build: hist saves per-edge rank -> scatter is atomic-free
    hist_kernel<<<(N_EDGES + 255) / 256, 256, 0, stream>>>(ei, cnt, rank, N_EDGES);
    int nb = (N_NODES + 1023) / 1024;
    scan1<<<nb, 256, 0, stream>>>(cnt, off, bsum, N_NODES);
    scan3<<<(N_NODES + 1 + 255) / 256, 256, 0, stream>>>(off, bsum, N_NODES, nb);
    scatter_kernel<<<(N_EDGES + 255) / 256, 256, 0, stream>>>(ei, wgt, sim, off, rank,
                                                              edat, N_EDGES);

    int agrid = (N_NODES + 3) / 4;

    // layer 0: xb [N,96] -> h1b [N,128]
    agg_pair<48><<<agrid, 256, 0, stream>>>((const uint32_tt*)xb, off, edat,
                                            (uint32_tt*)aggRb, (uint32_tt*)aggIb, N_NODES);
    gemm_mfma<96, 128, 128, 2, 2, 4, 4, true, false, 3>
        <<<(N_NODES + 127) / 128, 256, 0, stream>>>(aggRb, aggIb, xb, BT0, cb[0], lb[0],
                                                    h1b, N_NODES);
    // layer 1 + Y projection fused: h1b -> (h2 in LDS) -> Yb [N,96]
    agg_pair<64><<<agrid, 256, 0, stream>>>((const uint32_tt*)h1b, off, edat,
                                            (uint32_tt*)aggRb, (uint32_tt*)aggIb, N_NODES);
    gemm_l1y<<<(N_NODES + 127) / 128, 256, 0, stream>>>(aggRb, aggIb, h1b, BT1, BT2,
                                                        cb[1], lb[1], Yb, N_NODES);
    // layer 2: fused aggregate + bias + relu (edge pairs, no duplicate lanes)
    agg_out<<<agrid, 256, 0, stream>>>((const uint32_tt*)Yb, off, edat, cb[2], lb[2],
                                       outp, N_NODES);
}

// Round 9
// 251.806 us; speedup vs baseline: 3.6720x; 1.0321x over previous
//
#include <hip/hip_runtime.h>

#define N_NODES 50000
#define N_EDGES 600000
#define E_PAD_MAX (N_EDGES + N_NODES * 7)   // padded edge capacity

using bf16x8 = __attribute__((ext_vector_type(8))) short;
using f32x4  = __attribute__((ext_vector_type(4))) float;
using f32x2  = __attribute__((ext_vector_type(2))) float;
using u32x2  = __attribute__((ext_vector_type(2))) unsigned int;  // NT-store-able
typedef unsigned int uint32_tt;
typedef unsigned long long u64;

__device__ __forceinline__ unsigned short f2bf(float f) {
    union { float f; unsigned int u; } v; v.f = f;
    unsigned int u = v.u;
    return (unsigned short)((u + 0x7fffu + ((u >> 16) & 1u)) >> 16);  // RNE
}
__device__ __forceinline__ float bf2f(unsigned int h16) {
    union { unsigned int u; float f; } v; v.u = h16 << 16;
    return v.f;
}
// unpack 2 packed bf16 -> f32x2 {lo, hi}
__device__ __forceinline__ f32x2 unpk(uint32_tt w) {
    union { uint32_tt u; float f; } a, b;
    a.u = w << 16; b.u = w & 0xffff0000u;
    return (f32x2){a.f, b.f};
}
// async global->LDS, 16B per lane: HW writes lds_base + lane*16 (wave-uniform
// base). Drained by the vmcnt(0) the compiler emits at __syncthreads().
__device__ __forceinline__ void gl_lds16(const void* g, void* l) {
    __builtin_amdgcn_global_load_lds(
        (const __attribute__((address_space(1))) unsigned int*)g,
        (__attribute__((address_space(3))) unsigned int*)l, 16, 0, 0);
}

// ---------------- merged prep (runs FIRST, depends on nothing) ---------------
__global__ void prep_kernel(
    const float* __restrict__ x0, unsigned short* __restrict__ xb,
    const float* __restrict__ wr0, const float* __restrict__ wi0,
    const float* __restrict__ lw0, unsigned short* __restrict__ BT0,
    const float* __restrict__ wr1, const float* __restrict__ wi1,
    const float* __restrict__ lw1, unsigned short* __restrict__ BT1,
    const float* __restrict__ wr2, const float* __restrict__ wi2,
    const float* __restrict__ lw2, unsigned short* __restrict__ BT2,
    int* __restrict__ cnt, uint2* __restrict__ edat, int n) {
    int tid = blockIdx.x * 256 + threadIdx.x;
    int nth = gridDim.x * 256;
    for (int i = tid; i < N_NODES; i += nth) cnt[i] = 0;
    uint2 z; z.x = 0u; z.y = 0u;
    for (int i = tid; i < E_PAD_MAX; i += nth) edat[i] = z;

    int i = tid;
    int nconv = n * 96;
    if (i < nconv) {
        int r = i / 96, c = i - r * 96;
        xb[i] = (c < 75) ? f2bf(x0[r * 75 + c]) : (unsigned short)0;
        return;
    }
    i -= nconv;
    if (i < 128 * 288) {   // BT0: CIN=75 CINP=96 COUT=128
        int nn = i / 288, k = i - nn * 288;
        int part = k / 96, kk = k - part * 96;
        float v = 0.f;
        if (kk < 75) {
            if (part == 0)      v = wr0[kk * 128 + nn];
            else if (part == 1) v = -wi0[kk * 128 + nn];
            else                v = lw0[nn * 75 + kk];
        }
        BT0[i] = f2bf(v);
        return;
    }
    i -= 128 * 288;
    if (i < 128 * 384) {   // BT1: CIN=CINP=128 COUT=128
        int nn = i / 384, k = i - nn * 384;
        int part = k >> 7, kk = k & 127;
        float v;
        if (part == 0)      v = wr1[kk * 128 + nn];
        else if (part == 1) v = -wi1[kk * 128 + nn];
        else                v = lw1[nn * 128 + kk];
        BT1[i] = f2bf(v);
        return;
    }
    i -= 128 * 384;
    if (i < 96 * 128) {    // BT2 (Y-projection): [96 rows][128 k] = [wr2|-wi2|lw2^T]
        int nn = i >> 7, k = i & 127;
        float v;
        if (nn < 32)      v = wr2[k * 32 + nn];
        else if (nn < 64) v = -wi2[k * 32 + (nn - 32)];
        else              v = lw2[(nn - 64) * 128 + k];
        BT2[i] = f2bf(v);
    }
}

// ---------------- CSR build (degrees padded to multiple of 8) ----------------
// R17/R20: cooperative fusion is DEAD both ways (256 blocks: phases starve;
// 1792 blocks: grid.sync spin ~680us across non-coherent XCD L2s). 4-kernel
// chain at full width is the verified form. Do not revisit.

__global__ void hist_kernel(const int* __restrict__ ei, int* __restrict__ cnt,
                            int* __restrict__ rank, int E) {
    int e = blockIdx.x * 256 + threadIdx.x;
    if (e < E) rank[e] = atomicAdd(&cnt[ei[E + e]], 1);
}

__global__ void scan1(const int* __restrict__ deg, int* __restrict__ out,
                      int* __restrict__ bsum, int n) {
    __shared__ int s[256];
    int t = threadIdx.x;
    int base = blockIdx.x * 1024 + t * 4;
    int v0 = (base + 0 < n) ? ((deg[base + 0] + 7) & ~7) : 0;
    int v1 = (base + 1 < n) ? ((deg[base + 1] + 7) & ~7) : 0;
    int v2 = (base + 2 < n) ? ((deg[base + 2] + 7) & ~7) : 0;
    int v3 = (base + 3 < n) ? ((deg[base + 3] + 7) & ~7) : 0;
    int tsum = v0 + v1 + v2 + v3;
    s[t] = tsum;
    __syncthreads();
    for (int off = 1; off < 256; off <<= 1) {
        int tmp = (t >= off) ? s[t - off] : 0;
        __syncthreads();
        s[t] += tmp;
        __syncthreads();
    }
    int excl = s[t] - tsum;
    if (base + 0 < n) out[base + 0] = excl;
    if (base + 1 < n) out[base + 1] = excl + v0;
    if (base + 2 < n) out[base + 2] = excl + v0 + v1;
    if (base + 3 < n) out[base + 3] = excl + v0 + v1 + v2;
    if (t == 255) bsum[blockIdx.x] = s[255];
}

// scan3 with scan2 folded in (thread 0 sums <=49 L2-hot block totals)
__global__ void scan3(int* __restrict__ off, const int* __restrict__ bsum,
                      int n, int nb) {
    __shared__ int sp;
    int b = blockIdx.x, t = threadIdx.x;
    int seg = b >> 2;
    if (t == 0) {
        int acc = 0;
        for (int k = 0; k < seg; ++k) acc += bsum[k];
        sp = acc;
    }
    __syncthreads();
    int i = b * 256 + t;
    if (i < n) off[i] += sp;
    if (i == n) {
        int tot = sp;
        for (int k = seg; k < nb; ++k) tot += bsum[k];
        off[n] = tot;
    }
}

// atomic-free scatter: p = off[d] + rank[e]
__global__ void scatter_kernel(const int* __restrict__ ei, const float* __restrict__ w,
                               const float* __restrict__ sim, const int* __restrict__ off,
                               const int* __restrict__ rank, uint2* __restrict__ edat,
                               int E) {
    int e = blockIdx.x * 256 + threadIdx.x;
    if (e >= E) return;
    int s = ei[e], d = ei[E + e];
    int p = off[d] + rank[e];
    float wt = w[e];
    uint2 m;
    m.x = (unsigned)s;
    m.y = (uint32_tt)f2bf(wt * sim[2 * e]) |
          ((uint32_tt)f2bf(wt * sim[2 * e + 1]) << 16);
    edat[p] = m;
}

// ---------------- aggregation: one wave per node, edge-PAIR lanes ------------
// CLOSED POOL (R13/R15/R16/R18/R21): aggs are at the random-gather line-
// throughput floor (~3.3M random 128B lines across 3 passes). Pipelining,
// 2-wave, chunking, packed-FMA, NT-stores all neutral or worse. Structure:
// 8 edges/iter, metadata in SGPRs via readfirstlane, 1-batch-ahead prefetch,
// 2 edges per gather inst, f32x2 packed accumulate, NT output stores.
template <int CU2>  // uint32s per feature row (= CINP/2): 48 or 64
__global__ __launch_bounds__(256) void agg_pair(
    const uint32_tt* __restrict__ x, const int* __restrict__ off,
    const uint2* __restrict__ edat, uint32_tt* __restrict__ aggR,
    uint32_tt* __restrict__ aggI, int n) {
    constexpr int P = CU2 / 2;            // uint2 slots per row (24 or 32)
    constexpr int RB = CU2 * 4;           // row bytes (192 or 256)
    int wave = threadIdx.x >> 6;
    int lane = threadIdx.x & 63;
    int node = __builtin_amdgcn_readfirstlane(blockIdx.x * 4 + wave);
    if (node >= n) return;
    int j = lane >> 5;                    // edge slot within pair
    int c = lane & 31;
    int lc = (P == 32) ? c : (c < P ? c : P - 1);   // clamped uint2 slot
    f32x2 arA = (f32x2){0.f, 0.f}, arB = (f32x2){0.f, 0.f};
    f32x2 aiA = (f32x2){0.f, 0.f}, aiB = (f32x2){0.f, 0.f};
    int e0 = __builtin_amdgcn_readfirstlane(off[node]);
    int e1 = __builtin_amdgcn_readfirstlane(off[node + 1]);

    if (e0 < e1) {
        uint2 mn[8];
        int soc[4]; float crc[4], cic[4];
        uint2 wc[4];
        {
            uint2 m0[8];
#pragma unroll
            for (int k = 0; k < 8; ++k) m0[k] = edat[e0 + k];
            int so8[8]; float cr8[8], ci8[8];
#pragma unroll
            for (int k = 0; k < 8; ++k) {
                int s = __builtin_amdgcn_readfirstlane((int)m0[k].x);
                int pk = __builtin_amdgcn_readfirstlane((int)m0[k].y);
                so8[k] = s * RB;          // scalar multiply (SALU)
                cr8[k] = bf2f((unsigned)pk & 0xffffu);
                ci8[k] = bf2f((unsigned)pk >> 16);
            }
#pragma unroll
            for (int k = 0; k < 4; ++k) {   // per-half pair-member select
                soc[k] = j ? so8[2 * k + 1] : so8[2 * k];
                crc[k] = j ? cr8[2 * k + 1] : cr8[2 * k];
                cic[k] = j ? ci8[2 * k + 1] : ci8[2 * k];
            }
            int nb = (e0 + 8 < e1) ? e0 + 8 : e0;
#pragma unroll
            for (int k = 0; k < 8; ++k) mn[k] = edat[nb + k];
#pragma unroll
            for (int k = 0; k < 4; ++k)
                wc[k] = *(const uint2*)((const char*)x + (unsigned)soc[k] +
                                        (unsigned)(lc * 8));
        }
        for (int e = e0;; e += 8) {
            bool more = (e + 8 < e1);      // wave-uniform
            int son[4]; float crn[4], cin_[4]; uint2 wn[4];
            if (more) {
                int so8[8]; float cr8[8], ci8[8];
#pragma unroll
                for (int k = 0; k < 8; ++k) {
                    int s = __builtin_amdgcn_readfirstlane((int)mn[k].x);
                    int pk = __builtin_amdgcn_readfirstlane((int)mn[k].y);
                    so8[k] = s * RB;
                    cr8[k] = bf2f((unsigned)pk & 0xffffu);
                    ci8[k] = bf2f((unsigned)pk >> 16);
                }
#pragma unroll
                for (int k = 0; k < 4; ++k) {
                    son[k] = j ? so8[2 * k + 1] : so8[2 * k];
                    crn[k] = j ? cr8[2 * k + 1] : cr8[2 * k];
                    cin_[k] = j ? ci8[2 * k + 1] : ci8[2 * k];
                }
                int nb = (e + 16 < e1) ? e + 16 : e + 8;
#pragma unroll
                for (int k = 0; k < 8; ++k) mn[k] = edat[nb + k];
#pragma unroll
                for (int k = 0; k < 4; ++k)
                    wn[k] = *(const uint2*)((const char*)x + (unsigned)son[k] +
                                            (unsigned)(lc * 8));
            }
#pragma unroll
            for (int k = 0; k < 4; ++k) {
                f32x2 w0 = unpk(wc[k].x);          // {lo0, hi0}
                f32x2 w1 = unpk(wc[k].y);          // {lo1, hi1}
                f32x2 cr2 = (f32x2){crc[k], crc[k]};
                f32x2 ci2 = (f32x2){cic[k], cic[k]};
                arA = cr2 * w0 + arA;              // contracts to v_pk_fma_f32
                arB = cr2 * w1 + arB;
                aiA = ci2 * w0 + aiA;
                aiB = ci2 * w1 + aiB;
            }
            if (!more) break;
#pragma unroll
            for (int k = 0; k < 4; ++k) {
                crc[k] = crn[k]; cic[k] = cin_[k]; wc[k] = wn[k];
            }
        }
    }
    // combine the two edge-slot halves (lane l <-> l+32 share slot lc)
    float ar0 = arA.x, ar1 = arA.y, ar2 = arB.x, ar3 = arB.y;
    float ai0 = aiA.x, ai1 = aiA.y, ai2 = aiB.x, ai3 = aiB.y;
    ar0 += __shfl_xor(ar0, 32); ar1 += __shfl_xor(ar1, 32);
    ar2 += __shfl_xor(ar2, 32); ar3 += __shfl_xor(ar3, 32);
    ai0 += __shfl_xor(ai0, 32); ai1 += __shfl_xor(ai1, 32);
    ai2 += __shfl_xor(ai2, 32); ai3 += __shfl_xor(ai3, 32);
    if (lane < P) {
        u32x2 oR, oI;
        oR.x = (uint32_tt)f2bf(ar0) | ((uint32_tt)f2bf(ar1) << 16);
        oR.y = (uint32_tt)f2bf(ar2) | ((uint32_tt)f2bf(ar3) << 16);
        oI.x = (uint32_tt)f2bf(ai0) | ((uint32_tt)f2bf(ai1) << 16);
        oI.y = (uint32_tt)f2bf(ai2) | ((uint32_tt)f2bf(ai3) << 16);
        __builtin_nontemporal_store(oR, (u32x2*)(aggR + (size_t)node * CU2) + lane);
        __builtin_nontemporal_store(oI, (u32x2*)(aggI + (size_t)node * CU2) + lane);
    }
}

// ---------------- layer-2 fused aggregate + bias + relu + store --------------
// Y [n][48 dwords]: 0-15 Yr, 16-31 Yin, 32-47 lin (bf16 pairs).
// Pair structure (R15); packed f32x2 accumulate (R16). Reduction: xor32
// (edge slots) then xor16 (cr*Yr + ci*Yi). DO NOT reintroduce lane-dependent
// selects across private arrays (R6/R12 demotion).
__global__ __launch_bounds__(256) void agg_out(
    const uint32_tt* __restrict__ Y, const int* __restrict__ off,
    const uint2* __restrict__ edat, const float* __restrict__ cb,
    const float* __restrict__ lb, float* __restrict__ out, int n) {
    int wave = threadIdx.x >> 6;
    int lane = threadIdx.x & 63;
    int node = __builtin_amdgcn_readfirstlane(blockIdx.x * 4 + wave);
    if (node >= n) return;
    int j = lane >> 5;                 // edge slot within pair
    int lc = lane & 31;                // dword within [Yr|Yi]
    int usei = lc >> 4;                // 0: Yr w/ cr, 1: Yi w/ ci
    f32x2 acc = (f32x2){0.f, 0.f};
    int e0 = __builtin_amdgcn_readfirstlane(off[node]);
    int e1 = __builtin_amdgcn_readfirstlane(off[node + 1]);

    if (e0 < e1) {
        uint2 mn[8];
        int soc[4]; float cc[4]; uint32_tt wc[4];
        {
            uint2 m0[8];
#pragma unroll
            for (int k = 0; k < 8; ++k) m0[k] = edat[e0 + k];
            int so8[8]; float cr8[8], ci8[8];
#pragma unroll
            for (int k = 0; k < 8; ++k) {
                int s = __builtin_amdgcn_readfirstlane((int)m0[k].x);
                int pk = __builtin_amdgcn_readfirstlane((int)m0[k].y);
                so8[k] = s * 192;      // Y row = 48 dwords
                cr8[k] = bf2f((unsigned)pk & 0xffffu);
                ci8[k] = bf2f((unsigned)pk >> 16);
            }
#pragma unroll
            for (int k = 0; k < 4; ++k) {
                soc[k] = j ? so8[2 * k + 1] : so8[2 * k];
                float a = j ? cr8[2 * k + 1] : cr8[2 * k];
                float b = j ? ci8[2 * k + 1] : ci8[2 * k];
                cc[k] = usei ? b : a;
            }
            int nb = (e0 + 8 < e1) ? e0 + 8 : e0;
#pragma unroll
            for (int k = 0; k < 8; ++k) mn[k] = edat[nb + k];
#pragma unroll
            for (int k = 0; k < 4; ++k)
                wc[k] = *(const uint32_tt*)((const char*)Y + (unsigned)soc[k] +
                                            (unsigned)(lc * 4));
        }
        for (int e = e0;; e += 8) {
            bool more = (e + 8 < e1);
            int son[4]; float cn[4]; uint32_tt wn[4];
            if (more) {
                int so8[8]; float cr8[8], ci8[8];
#pragma unroll
                for (int k = 0; k < 8; ++k) {
                    int s = __builtin_amdgcn_readfirstlane((int)mn[k].x);
                    int pk = __builtin_amdgcn_readfirstlane((int)mn[k].y);
                    so8[k] = s * 192;
                    cr8[k] = bf2f((unsigned)pk & 0xffffu);
                    ci8[k] = bf2f((unsigned)pk >> 16);
                }
#pragma unroll
                for (int k = 0; k < 4; ++k) {
                    son[k] = j ? so8[2 * k + 1] : so8[2 * k];
                    float a = j ? cr8[2 * k + 1] : cr8[2 * k];
                    float b = j ? ci8[2 * k + 1] : ci8[2 * k];
                    cn[k] = usei ? b : a;
                }
                int nb = (e + 16 < e1) ? e + 16 : e + 8;
#pragma unroll
                for (int k = 0; k < 8; ++k) mn[k] = edat[nb + k];
#pragma unroll
                for (int k = 0; k < 4; ++k)
                    wn[k] = *(const uint32_tt*)((const char*)Y + (unsigned)son[k] +
                                                (unsigned)(lc * 4));
            }
#pragma unroll
            for (int k = 0; k < 4; ++k) {
                f32x2 wv = unpk(wc[k]);
                f32x2 c2 = (f32x2){cc[k], cc[k]};
                acc = c2 * wv + acc;       // contracts to v_pk_fma_f32
            }
            if (!more) break;
#pragma unroll
            for (int k = 0; k < 4; ++k) { cc[k] = cn[k]; wc[k] = wn[k]; }
        }
    }
    // sum edge slots (xor 32), then combine cr*Yr + ci*Yi halves (xor 16)
    float alo = acc.x, ahi = acc.y;
    alo += __shfl_xor(alo, 32); alo += __shfl_xor(alo, 16);
    ahi += __shfl_xor(ahi, 32); ahi += __shfl_xor(ahi, 16);
    if (lane < 16) {
        uint32_tt lin = Y[(size_t)node * 48 + 32 + lane];
        int c0 = 2 * lane, c1 = 2 * lane + 1;
        float v0 = alo + bf2f(lin & 0xffffu) + cb[c0] + lb[c0];
        float v1 = ahi + bf2f(lin >> 16) + cb[c1] + lb[c1];
        float2 r;
        r.x = v0 > 0.f ? v0 : 0.f;
        r.y = v1 > 0.f ? v1 : 0.f;
        ((float2*)out)[(size_t)node * 16 + lane] = r;
    }
}

// ---------------- bf16 MFMA GEMM (layer 0) -----------------------------------
// R23: staging via global_load_lds width=16 (async, no VGPR round-trip, no
// staging VALU). LDS is LINEAR [rows][32] (gl_lds writes base+lane*16 — pads
// break it, m104). Bank conflicts handled by 2-bit XOR swizzle carried in
// the per-lane GLOBAL address (kslot = (lane&3)^(row&3)) and undone at the
// fragment read (ksw = (kh^(ml&3))*8): each row's 4 slots land in distinct
// 16B bank groups -> every bank serves exactly 32B per b128 access (optimal).
// R20: BM=128 verified (BM=64 neutral-worse).
template <int CINP, int COUT, int BM, int WM, int WN, int MT, int NT,
          bool OUT_BF16, bool RAW, int PARTS>
__global__ __launch_bounds__(256) void gemm_mfma(
    const unsigned short* __restrict__ A0, const unsigned short* __restrict__ A1,
    const unsigned short* __restrict__ A2, const unsigned short* __restrict__ BT,
    const float* __restrict__ cb, const float* __restrict__ lb,
    void* __restrict__ outv, int n) {
    constexpr int KTOT = PARTS * CINP;
    constexpr int NCH = KTOT / 32;
    constexpr int CPP = CINP / 32;
    __shared__ unsigned short sA[BM][32];
    __shared__ unsigned short sB[COUT][32];

    int t = threadIdx.x;
    int lane = t & 63, wave = t >> 6;
    int wm = wave / WN, wn = wave % WN;
    int ml = lane & 15, kh = lane >> 4;
    int node0 = blockIdx.x * BM;
    int rsub = lane >> 2;                       // staging: row within 16-row group
    int ks   = ((lane & 3) ^ (rsub & 3)) * 8;   // staging: swizzled k-slot (ushorts)
    int ksw  = (kh ^ (ml & 3)) * 8;             // read: matching unswizzle

    const unsigned short* Asrc[3] = {A0, A1, A2};

    f32x4 acc[MT][NT];
#pragma unroll
    for (int mt = 0; mt < MT; ++mt)
#pragma unroll
        for (int nt = 0; nt < NT; ++nt) acc[mt][nt] = (f32x4){0.f, 0.f, 0.f, 0.f};

    for (int c = 0; c < NCH; ++c) {
        int part = (PARTS == 1) ? 0 : (c / CPP);
        int kk = (c - part * CPP) * 32;
        const unsigned short* __restrict__ Ap = Asrc[part];
        __syncthreads();
#pragma unroll
        for (int g = 0; g < BM / 64; ++g) {     // 16 rows per wave-instruction
            int q = wave + g * 4;
            int row = q * 16 + rsub;
            int node = node0 + row;
            if (node >= n) node = n - 1;
            gl_lds16(Ap + (size_t)node * CINP + kk + ks, &sA[q * 16][0]);
        }
#pragma unroll
        for (int g = 0; g < COUT / 64; ++g) {
            int q = wave + g * 4;
            int row = q * 16 + rsub;
            gl_lds16(BT + (size_t)row * KTOT + c * 32 + ks, &sB[q * 16][0]);
        }
        __syncthreads();                        // drains vmcnt -> LDS visible
        bf16x8 af[MT], bfr[NT];
#pragma unroll
        for (int mt = 0; mt < MT; ++mt)
            af[mt] = *(const bf16x8*)&sA[wm * (MT * 16) + mt * 16 + ml][ksw];
#pragma unroll
        for (int nt = 0; nt < NT; ++nt)
            bfr[nt] = *(const bf16x8*)&sB[wn * (NT * 16) + nt * 16 + ml][ksw];
#pragma unroll
        for (int mt = 0; mt < MT; ++mt)
#pragma unroll
            for (int nt = 0; nt < NT; ++nt)
                acc[mt][nt] = __builtin_amdgcn_mfma_f32_16x16x32_bf16(
                    af[mt], bfr[nt], acc[mt][nt], 0, 0, 0);
    }

    int row0 = kh * 4;
#pragma unroll
    for (int nt = 0; nt < NT; ++nt) {
        int col = wn * (NT * 16) + nt * 16 + ml;
        float bias = RAW ? 0.f : (cb[col] + lb[col]);
#pragma unroll
        for (int mt = 0; mt < MT; ++mt) {
#pragma unroll
            for (int r = 0; r < 4; ++r) {
                int node = node0 + wm * (MT * 16) + mt * 16 + row0 + r;
                if (node < n) {
                    float v = acc[mt][nt][r] + bias;
                    if (!RAW) v = v > 0.f ? v : 0.f;
                    if (OUT_BF16)
                        ((unsigned short*)outv)[(size_t)node * COUT + col] = f2bf(v);
                    else
                        ((float*)outv)[(size_t)node * COUT + col] = v;
                }
            }
        }
    }
}

// ---------------- fused layer-1 GEMM + Y projection --------------------------
// Stage 1: h2 = relu([aggR|aggI|h1] @ BT1^T + b1)  -> LDS (bf16, never global)
// Stage 2: Y  = h2 @ BT2^T  (96 cols; BT2 frags from global, 24.6KB L1-hot)
// R23: stage-1 staging via global_load_lds + XOR swizzle (see gemm_mfma).
__global__ __launch_bounds__(256) void gemm_l1y(
    const unsigned short* __restrict__ A0, const unsigned short* __restrict__ A1,
    const unsigned short* __restrict__ A2, const unsigned short* __restrict__ BT,
    const unsigned short* __restrict__ BT2, const float* __restrict__ cb,
    const float* __restrict__ lb, unsigned short* __restrict__ Yout, int n) {
    constexpr int PH = 136;   // h2 LDS stride (16B-aligned rows)
    __shared__ unsigned short sA[128][32];
    __shared__ unsigned short sB[128][32];
    __shared__ unsigned short sH[128][PH];

    int t = threadIdx.x;
    int lane = t & 63, wave = t >> 6;
    int wm = wave >> 1, wn = wave & 1;
    int ml = lane & 15, kh = lane >> 4;
    int node0 = blockIdx.x * 128;
    int rsub = lane >> 2;
    int ks   = ((lane & 3) ^ (rsub & 3)) * 8;
    int ksw  = (kh ^ (ml & 3)) * 8;
    const unsigned short* Asrc[3] = {A0, A1, A2};

    f32x4 acc[4][4];
#pragma unroll
    for (int mt = 0; mt < 4; ++mt)
#pragma unroll
        for (int nt = 0; nt < 4; ++nt) acc[mt][nt] = (f32x4){0.f, 0.f, 0.f, 0.f};

    for (int c = 0; c < 12; ++c) {          // KTOT=384, chunks of 32
        int part = c >> 2;
        int kk = (c & 3) * 32;
        const unsigned short* __restrict__ Ap = Asrc[part];
        __syncthreads();
#pragma unroll
        for (int g = 0; g < 2; ++g) {
            int q = wave + g * 4;
            int row = q * 16 + rsub;
            int node = node0 + row;
            if (node >= n) node = n - 1;
            gl_lds16(Ap + (size_t)node * 128 + kk + ks, &sA[q * 16][0]);
        }
#pragma unroll
        for (int g = 0; g < 2; ++g) {
            int q = wave + g * 4;
            int row = q * 16 + rsub;
            gl_lds16(BT + (size_t)row * 384 + c * 32 + ks, &sB[q * 16][0]);
        }
        __syncthreads();
        bf16x8 af[4], bfr[4];
#pragma unroll
        for (int mt = 0; mt < 4; ++mt)
            af[mt] = *(const bf16x8*)&sA[wm * 64 + mt * 16 + ml][ksw];
#pragma unroll
        for (int nt = 0; nt < 4; ++nt)
            bfr[nt] = *(const bf16x8*)&sB[wn * 64 + nt * 16 + ml][ksw];
#pragma unroll
        for (int mt = 0; mt < 4; ++mt)
#pragma unroll
            for (int nt = 0; nt < 4; ++nt)
                acc[mt][nt] = __builtin_amdgcn_mfma_f32_16x16x32_bf16(
                    af[mt], bfr[nt], acc[mt][nt], 0, 0, 0);
    }

    // epilogue 1: bias + relu -> bf16 -> sH[node][col]  (h2 stays on-chip)
    int row0 = kh * 4;
#pragma unroll
    for (int nt = 0; nt < 4; ++nt) {
        int col = wn * 64 + nt * 16 + ml;
        float bias = cb[col] + lb[col];
#pragma unroll
        for (int mt = 0; mt < 4; ++mt) {
#pragma unroll
            for (int r = 0; r < 4; ++r) {
                int nl = wm * 64 + mt * 16 + row0 + r;
                float v = acc[mt][nt][r] + bias;
                sH[nl][col] = f2bf(v > 0.f ? v : 0.f);
            }
        }
    }
    __syncthreads();

    // stage 2: Y[node][ycol] = sum_k h2[node][k] * BT2[ycol][k]
    f32x4 acc2[4][3];
#pragma unroll
    for (int mt = 0; mt < 4; ++mt)
#pragma unroll
        for (int nt = 0; nt < 3; ++nt) acc2[mt][nt] = (f32x4){0.f, 0.f, 0.f, 0.f};
    for (int c2 = 0; c2 < 4; ++c2) {
        bf16x8 af[4], bfr[3];
#pragma unroll
        for (int mt = 0; mt < 4; ++mt)
            af[mt] = *(const bf16x8*)&sH[wm * 64 + mt * 16 + ml][c2 * 32 + kh * 8];
#pragma unroll
        for (int nt = 0; nt < 3; ++nt) {
            int ycol = wn * 48 + nt * 16 + ml;
            bfr[nt] = *(const bf16x8*)(BT2 + (size_t)ycol * 128 + c2 * 32 + kh * 8);
        }
#pragma unroll
        for (int mt = 0; mt < 4; ++mt)
#pragma unroll
            for (int nt = 0; nt < 3; ++nt)
                acc2[mt][nt] = __builtin_amdgcn_mfma_f32_16x16x32_bf16(
                    af[mt], bfr[nt], acc2[mt][nt], 0, 0, 0);
    }
#pragma unroll
    for (int nt = 0; nt < 3; ++nt) {
        int ycol = wn * 48 + nt * 16 + ml;
#pragma unroll
        for (int mt = 0; mt < 4; ++mt) {
#pragma unroll
            for (int r = 0; r < 4; ++r) {
                int node = node0 + wm * 64 + mt * 16 + row0 + r;
                if (node < n)
                    Yout[(size_t)node * 96 + ycol] = f2bf(acc2[mt][nt][r]);
            }
        }
    }
}

// ---------------- launch ----------------

extern "C" void kernel_launch(void* const* d_in, const int* in_sizes, int n_in,
                              void* d_out, int out_size, void* d_ws, size_t ws_size,
                              hipStream_t stream) {
    const float* x0  = (const float*)d_in[0];
    const int*   ei  = (const int*)d_in[1];
    const float* wgt = (const float*)d_in[2];
    const float* sim = (const float*)d_in[3];
    const float *wr[3], *wi[3], *cb[3], *lw[3], *lb[3];
    for (int l = 0; l < 3; ++l) {
        wr[l] = (const float*)d_in[4 + 5 * l];
        wi[l] = (const float*)d_in[5 + 5 * l];
        cb[l] = (const float*)d_in[6 + 5 * l];
        lw[l] = (const float*)d_in[7 + 5 * l];
        lb[l] = (const float*)d_in[8 + 5 * l];
    }

    char* p = (char*)d_ws;
    auto alloc = [&](size_t bytes) -> void* {
        void* r = p;
        p += (bytes + 255) & ~(size_t)255;
        return r;
    };
    int*   off  = (int*)alloc((N_NODES + 1) * 4);
    int*   cnt  = (int*)alloc(N_NODES * 4);
    int*   bsum = (int*)alloc(256);
    int*   rank = (int*)alloc((size_t)N_EDGES * 4);
    uint2* edat = (uint2*)alloc((size_t)E_PAD_MAX * 8);
    unsigned short* xb    = (unsigned short*)alloc((size_t)N_NODES * 96 * 2);
    unsigned short* aggRb = (unsigned short*)alloc((size_t)N_NODES * 128 * 2);
    unsigned short* aggIb = (unsigned short*)alloc((size_t)N_NODES * 128 * 2);
    unsigned short* h1b   = (unsigned short*)alloc((size_t)N_NODES * 128 * 2);
    unsigned short* Yb    = (unsigned short*)alloc((size_t)N_NODES * 96 * 2);
    unsigned short* BT0   = (unsigned short*)alloc((size_t)128 * 288 * 2);
    unsigned short* BT1   = (unsigned short*)alloc((size_t)128 * 384 * 2);
    unsigned short* BT2   = (unsigned short*)alloc((size_t)96 * 128 * 2);
    float* outp = (float*)d_out;

    // merged prep FIRST (also zeroes cnt + edat; depends on nothing)
    {
        int total = N_NODES * 96 + 128 * 288 + 128 * 384 + 96 * 128;
        prep_kernel<<<(total + 255) / 256, 256, 0, stream>>>(
            x0, xb, wr[0], wi[0], lw[0], BT0, wr[1], wi[1], lw[1], BT1,
            wr[2], wi[2], lw[2], BT2, cnt, edat, N_NODES);
    }
    // CSR build: hist saves per-edge rank -> scatter is atomic-free
    hist_kernel<<<(N_EDGES + 255) / 256, 256, 0, stream>>>(ei, cnt, rank, N_EDGES);
    int nb = (N_NODES + 1023) / 1024;
    scan1<<<nb, 256, 0, stream>>>(cnt, off, bsum, N_NODES);
    scan3<<<(N_NODES + 1 + 255) / 256, 256, 0, stream>>>(off, bsum, N_NODES, nb);
    scatter_kernel<<<(N_EDGES + 255) / 256, 256, 0, stream>>>(ei, wgt, sim, off, rank,
                                                              edat, N_EDGES);

    int agrid = (N_NODES + 3) / 4;

    // layer 0: xb [N,96] -> h1b [N,128]
    agg_pair<48><<<agrid, 256, 0, stream>>>((const uint32_tt*)xb, off, edat,
                                            (uint32_tt*)aggRb, (uint32_tt*)aggIb, N_NODES);
    gemm_mfma<96, 128, 128, 2, 2, 4, 4, true, false, 3>
        <<<(N_NODES + 127) / 128, 256, 0, stream>>>(aggRb, aggIb, xb, BT0, cb[0], lb[0],
                                                    h1b, N_NODES);
    // layer 1 + Y projection fused: h1b -> (h2 in LDS) -> Yb [N,96]
    agg_pair<64><<<agrid, 256, 0, stream>>>((const uint32_tt*)h1b, off, edat,
                                            (uint32_tt*)aggRb, (uint32_tt*)aggIb, N_NODES);
    gemm_l1y<<<(N_NODES + 127) / 128, 256, 0, stream>>>(aggRb, aggIb, h1b, BT1, BT2,
                                                        cb[1], lb[1], Yb, N_NODES);
    // layer 2: fused aggregate + bias + relu (edge pairs, no duplicate lanes)
    agg_out<<<agrid, 256, 0, stream>>>((const uint32_tt*)Yb, off, edat, cb[2], lb[2],
                                       outp, N_NODES);
}